// Round 15
// baseline (368.526 us; speedup 1.0000x reference)
//
#include <hip/hip_runtime.h>
#include <hip/hip_bf16.h>
#include <math.h>

#define NA 10000
#define NE 256000
#define FDIM 128
#define F3 384
#define NRBF 20
#define NLAYERS 3
#define NMOLS 100
#define CAP 96
#define NBINS 97
#define WROW 388  // padded w_lds row (bf16): conflict-free MFMA-C transpose (verified R6)
#define CUTOFF_F 5.0f
#define EPS_F 1e-8f
#define PI_F 3.14159265358979323846f

typedef __attribute__((ext_vector_type(8))) short bf16x8;
typedef __attribute__((ext_vector_type(4))) float f32x4;

// 12-byte fused record: {phi0, phi1, phi2, v0, v1, v2} bf16
struct pv6 { unsigned int u0, u1, u2; };

__device__ __forceinline__ float silu_f(float x) { return x / (1.0f + __expf(-x)); }

__device__ __forceinline__ unsigned short f2bf(float x) {
  unsigned u = __float_as_uint(x);
  return (unsigned short)((u + 0x7FFFu + ((u >> 16) & 1u)) >> 16);
}
__device__ __forceinline__ float bf2f(unsigned short u) {
  return __uint_as_float(((unsigned)u) << 16);
}
__device__ __forceinline__ float lo_f(unsigned int u) { return bf2f((unsigned short)(u & 0xFFFFu)); }
__device__ __forceinline__ float hi_f(unsigned int u) { return bf2f((unsigned short)(u >> 16)); }

// ---------------- fused geometry + bucket build (rbf: bf16, fcut pre-multiplied) ----------------
__global__ __launch_bounds__(256) void geom_build_kernel(
    const float* __restrict__ xyz, const int* __restrict__ nbrs,
    float* __restrict__ unitv, unsigned short* __restrict__ rbf_bf,
    float* __restrict__ fcut,
    int* __restrict__ deg, int* __restrict__ slot_e, int* __restrict__ slot_j) {
  int e = blockIdx.x * 256 + threadIdx.x;
  if (e >= NE) return;
  int i = nbrs[2 * e + 0], j = nbrs[2 * e + 1];
  float rx = xyz[3 * j + 0] - xyz[3 * i + 0];
  float ry = xyz[3 * j + 1] - xyz[3 * i + 1];
  float rz = xyz[3 * j + 2] - xyz[3 * i + 2];
  float d = sqrtf(rx * rx + ry * ry + rz * rz + EPS_F);
  if (d >= CUTOFF_F) return;
  float invd = 1.0f / d;
  float fc = 0.5f * (__cosf(PI_F * d / CUTOFF_F) + 1.0f);
  unitv[3 * e + 0] = rx * invd;
  unitv[3 * e + 1] = ry * invd;
  unitv[3 * e + 2] = rz * invd;
  fcut[e] = fc;
  float base = PI_F * d / CUTOFF_F;
  float sc = invd * fc;
#pragma unroll
  for (int k = 0; k < NRBF; k++)
    rbf_bf[(size_t)e * NRBF + k] = f2bf(__sinf((float)(k + 1) * base) * sc);
  int pos = atomicAdd(&deg[i], 1);
  if (pos < CAP) {
    slot_e[i * CAP + pos] = e;
    slot_j[i * CAP + pos] = j;
  }
}

// ---------------- degree-descending block order (counting sort; bitwise-neutral) ----------------
__global__ __launch_bounds__(256) void hist_kernel(const int* __restrict__ deg,
                                                   int* __restrict__ bins) {
  int n = blockIdx.x * 256 + threadIdx.x;
  if (n >= NA) return;
  int d = deg[n]; if (d > CAP) d = CAP;
  atomicAdd(&bins[CAP - d], 1);  // key 0 = largest degree
}

__global__ __launch_bounds__(128) void scan_bins_kernel(const int* __restrict__ bins,
                                                        int* __restrict__ offs) {
  if (threadIdx.x == 0) {
    int acc = 0;
    for (int k = 0; k < NBINS; k++) { offs[k] = acc; acc += bins[k]; }
  }
}

__global__ __launch_bounds__(256) void scatter_kernel(const int* __restrict__ deg,
                                                      const int* __restrict__ offs,
                                                      int* __restrict__ cur,
                                                      int* __restrict__ order) {
  int n = blockIdx.x * 256 + threadIdx.x;
  if (n >= NA) return;
  int d = deg[n]; if (d > CAP) d = CAP;
  int key = CAP - d;
  int pos = offs[key] + atomicAdd(&cur[key], 1);
  order[pos] = n;
}

// ---------------- single fused weight pack -> B-fragment bf16 layout ----------------
__device__ __forceinline__ void pack_one(const float* __restrict__ src,
                                         unsigned short* __restrict__ dst,
                                         int loc, int per, int N) {
  int lay = loc / per;
  int kn = loc - lay * per;
  int k = kn / N, n = kn - k * N;
  int kb = k >> 5, q = (k >> 3) & 3, j = k & 7, nt = n >> 4, c = n & 15;
  int NT = N >> 4;
  dst[(size_t)lay * per + (((kb * NT + nt) * 64 + (q * 16 + c)) * 8 + j)] = f2bf(src[loc]);
}

// dist_W padded pack: K=32 (rows 0..19 = dW, row 20 = db, rest 0), N=384
__device__ __forceinline__ void pack_dw(const float* __restrict__ dW,
                                        const float* __restrict__ db,
                                        unsigned short* __restrict__ dst, int loc) {
  int lay = loc / 12288;
  int kn = loc - lay * 12288;
  int k = kn / 384, n = kn - k * 384;
  float val = 0.0f;
  if (k < NRBF) val = dW[lay * NRBF * 384 + k * 384 + n];
  else if (k == NRBF) val = db[lay * 384 + n];
  int q = (k >> 3) & 3, j = k & 7, nt = n >> 4, c = n & 15;
  dst[(size_t)lay * 12288 + ((nt * 64 + (q * 16 + c)) * 8 + j)] = f2bf(val);
}

__global__ __launch_bounds__(256) void pack_all_kernel(
    const float* __restrict__ msgW1, const float* __restrict__ msgW2,
    const float* __restrict__ updU, const float* __restrict__ updV,
    const float* __restrict__ updW1, const float* __restrict__ updW2,
    const float* __restrict__ rW1, const float* __restrict__ distW,
    const float* __restrict__ distb, unsigned short* __restrict__ dst) {
  int t = blockIdx.x * 256 + threadIdx.x;
  if (t < 49152) pack_one(msgW1, dst, t, 16384, 128);
  else if (t < 196608) pack_one(msgW2, dst + 49152, t - 49152, 49152, 384);
  else if (t < 245760) pack_one(updU, dst + 196608, t - 196608, 16384, 128);
  else if (t < 294912) pack_one(updV, dst + 245760, t - 245760, 16384, 128);
  else if (t < 393216) pack_one(updW1, dst + 294912, t - 294912, 32768, 128);
  else if (t < 540672) pack_one(updW2, dst + 393216, t - 393216, 49152, 384);
  else if (t < 548864) pack_one(rW1, dst + 540672, t - 540672, 8192, 64);
  else if (t < 585728) pack_dw(distW, distb, dst + 548864, t - 548864);
}

// ---------------- layer-0 message MLP (fused s = emb[z] init); writes pv6 {phi, v=0} ----------------
__global__ __launch_bounds__(256) void msg0_mfma_kernel(
    const float* __restrict__ emb, const int* __restrict__ z, float* __restrict__ s_out,
    const unsigned short* __restrict__ pW1, const float* __restrict__ b1,
    const unsigned short* __restrict__ pW2, const float* __restrict__ b2,
    pv6* __restrict__ cmb) {
  __shared__ bf16x8 sA[4 * 64];
  __shared__ bf16x8 hA[4 * 64];
  int a0 = blockIdx.x * 16;
  int t = threadIdx.x;
  int lane = t & 63, w = t >> 6;
  {
    int kb = t >> 6, l = t & 63;
    int m = l & 15, q = l >> 4;
    int zi = z[a0 + m];
    const float* sp = emb + (size_t)zi * FDIM + kb * 32 + q * 8;
    float* so = s_out + (size_t)(a0 + m) * FDIM + kb * 32 + q * 8;
    bf16x8 c;
#pragma unroll
    for (int j = 0; j < 8; j++) {
      float v = sp[j];
      so[j] = v;
      c[j] = (short)f2bf(v);
    }
    sA[kb * 64 + l] = c;
  }
  __syncthreads();
  f32x4 accH[2];
#pragma unroll
  for (int t2 = 0; t2 < 2; t2++)
#pragma unroll
    for (int r = 0; r < 4; r++) accH[t2][r] = 0.0f;
  const bf16x8* W1f = (const bf16x8*)pW1;
#pragma unroll
  for (int kb = 0; kb < 4; kb++) {
    bf16x8 a = sA[kb * 64 + lane];
#pragma unroll
    for (int t2 = 0; t2 < 2; t2++) {
      bf16x8 b = W1f[(kb * 8 + 2 * w + t2) * 64 + lane];
      accH[t2] = __builtin_amdgcn_mfma_f32_16x16x32_bf16(a, b, accH[t2], 0, 0, 0);
    }
  }
  short* hs = (short*)hA;
#pragma unroll
  for (int t2 = 0; t2 < 2; t2++) {
    int n = w * 32 + t2 * 16 + (lane & 15);
    int kb = n >> 5, q = (n >> 3) & 3, j = n & 7;
    float bias = b1[n];
#pragma unroll
    for (int r = 0; r < 4; r++) {
      int m = (lane >> 4) * 4 + r;
      hs[(kb * 64 + q * 16 + m) * 8 + j] = (short)f2bf(silu_f(accH[t2][r] + bias));
    }
  }
  __syncthreads();
  f32x4 accP[3][2];
#pragma unroll
  for (int c3 = 0; c3 < 3; c3++)
#pragma unroll
    for (int t2 = 0; t2 < 2; t2++)
#pragma unroll
      for (int r = 0; r < 4; r++) accP[c3][t2][r] = 0.0f;
  const bf16x8* W2f = (const bf16x8*)pW2;
#pragma unroll
  for (int kb = 0; kb < 4; kb++) {
    bf16x8 a = hA[kb * 64 + lane];
#pragma unroll
    for (int c3 = 0; c3 < 3; c3++)
#pragma unroll
      for (int t2 = 0; t2 < 2; t2++) {
        bf16x8 b = W2f[(kb * 24 + c3 * 8 + 2 * w + t2) * 64 + lane];
        accP[c3][t2] = __builtin_amdgcn_mfma_f32_16x16x32_bf16(a, b, accP[c3][t2], 0, 0, 0);
      }
  }
#pragma unroll
  for (int t2 = 0; t2 < 2; t2++) {
    int g = (2 * w + t2) * 16 + (lane & 15);
    float bb0 = b2[g], bb1 = b2[FDIM + g], bb2 = b2[2 * FDIM + g];
#pragma unroll
    for (int r = 0; r < 4; r++) {
      int m = (lane >> 4) * 4 + r;
      unsigned p0 = f2bf(accP[0][t2][r] + bb0);
      unsigned p1 = f2bf(accP[1][t2][r] + bb1);
      unsigned p2 = f2bf(accP[2][t2][r] + bb2);
      pv6 rec;
      rec.u0 = p0 | (p1 << 16);
      rec.u1 = p2;
      rec.u2 = 0;
      cmb[(size_t)(a0 + m) * FDIM + g] = rec;
    }
  }
}

// ---------------- edge aggregation: 128 thr, 12B pv6 gather, degree-sorted block order ----------------
__global__ __launch_bounds__(128) void edge_kernel(
    const pv6* __restrict__ cmb, unsigned short* __restrict__ v_lin,
    float* __restrict__ s, const unsigned short* __restrict__ pDW,
    const int* __restrict__ deg, const int* __restrict__ slot_e,
    const int* __restrict__ slot_j, const unsigned short* __restrict__ rbf_bf,
    const float* __restrict__ fcut, const float* __restrict__ unitv,
    const int* __restrict__ order) {
  __shared__ bf16x8 aLDS[64];
  __shared__ unsigned short w_lds[16][WROW];
  __shared__ float l_u[16][3];
  __shared__ int l_j[16];
  int i = order[blockIdx.x];
  int t = threadIdx.x;
  int f = t;
  int lane = t & 63, w = t >> 6;
  int cnt = deg[i];
  if (cnt > CAP) cnt = CAP;
  int base = i * CAP;
  float acc_s = 0.f, av0 = 0.f, av1 = 0.f, av2 = 0.f;
  const bf16x8* Bf = (const bf16x8*)pDW;
  for (int c0 = 0; c0 < cnt; c0 += 16) {
    int ccnt = cnt - c0;
    if (ccnt > 16) ccnt = 16;
    __syncthreads();  // prev chunk's LDS reads done before overwrite
    if (t < 64) {
      int m = t & 15, q = t >> 4;
      bf16x8 a;
#pragma unroll
      for (int j = 0; j < 8; j++) a[j] = 0;
      int p = c0 + m;
      if (p < cnt) {
        int e = slot_e[base + p];
        const unsigned short* rb = rbf_bf + (size_t)e * NRBF;
#pragma unroll
        for (int j = 0; j < 8; j++) {
          int k = q * 8 + j;
          if (k < NRBF) a[j] = (short)rb[k];
          else if (k == NRBF) a[j] = (short)f2bf(fcut[e]);
        }
      }
      aLDS[t] = a;
    } else if (t < 80) {
      int idx = t - 64;
      int p = c0 + idx;
      if (p < cnt) {
        int e = slot_e[base + p];
        l_j[idx] = slot_j[base + p];
        l_u[idx][0] = unitv[3 * e + 0];
        l_u[idx][1] = unitv[3 * e + 1];
        l_u[idx][2] = unitv[3 * e + 2];
      }
    }
    __syncthreads();
    {
      bf16x8 a = aLDS[lane];
      int n0 = lane & 15, m0 = (lane >> 4) * 4;
#pragma unroll
      for (int tt = 0; tt < 12; tt++) {
        int nt = 12 * w + tt;
        f32x4 acc;
#pragma unroll
        for (int r = 0; r < 4; r++) acc[r] = 0.0f;
        acc = __builtin_amdgcn_mfma_f32_16x16x32_bf16(a, Bf[nt * 64 + lane], acc, 0, 0, 0);
        int n = nt * 16 + n0;
#pragma unroll
        for (int r = 0; r < 4; r++) w_lds[m0 + r][n] = f2bf(acc[r]);
      }
    }
    __syncthreads();
    int pp = 0;
    for (; pp + 2 <= ccnt; pp += 2) {
      int j0 = l_j[pp], j1 = l_j[pp + 1];
      pv6 R0 = cmb[(size_t)j0 * FDIM + f];
      pv6 R1 = cmb[(size_t)j1 * FDIM + f];
      float p00 = lo_f(R0.u0), p01 = hi_f(R0.u0), p02 = lo_f(R0.u1);
      float v00 = hi_f(R0.u1), v01 = lo_f(R0.u2), v02 = hi_f(R0.u2);
      float p10 = lo_f(R1.u0), p11 = hi_f(R1.u0), p12 = lo_f(R1.u1);
      float v10 = hi_f(R1.u1), v11 = lo_f(R1.u2), v12 = hi_f(R1.u2);
      float w00 = bf2f(w_lds[pp][f]), w01 = bf2f(w_lds[pp][FDIM + f]),
            w02 = bf2f(w_lds[pp][2 * FDIM + f]);
      float w10 = bf2f(w_lds[pp + 1][f]), w11 = bf2f(w_lds[pp + 1][FDIM + f]),
            w12 = bf2f(w_lds[pp + 1][2 * FDIM + f]);
      acc_s += p00 * w00 + p10 * w10;
      float i01 = p01 * w01, i02 = p02 * w02, i11 = p11 * w11, i12 = p12 * w12;
      av0 += i01 * v00 + i02 * l_u[pp][0] + i11 * v10 + i12 * l_u[pp + 1][0];
      av1 += i01 * v01 + i02 * l_u[pp][1] + i11 * v11 + i12 * l_u[pp + 1][1];
      av2 += i01 * v02 + i02 * l_u[pp][2] + i11 * v12 + i12 * l_u[pp + 1][2];
    }
    if (pp < ccnt) {
      int j0 = l_j[pp];
      pv6 R0 = cmb[(size_t)j0 * FDIM + f];
      float p00 = lo_f(R0.u0), p01 = hi_f(R0.u0), p02 = lo_f(R0.u1);
      float v00 = hi_f(R0.u1), v01 = lo_f(R0.u2), v02 = hi_f(R0.u2);
      float w00 = bf2f(w_lds[pp][f]), w01 = bf2f(w_lds[pp][FDIM + f]),
            w02 = bf2f(w_lds[pp][2 * FDIM + f]);
      acc_s += p00 * w00;
      float i01 = p01 * w01, i02 = p02 * w02;
      av0 += i01 * v00 + i02 * l_u[pp][0];
      av1 += i01 * v01 + i02 * l_u[pp][1];
      av2 += i01 * v02 + i02 * l_u[pp][2];
    }
  }
  // own-atom v add: cmb v-halves are 0 for layer 0, so unconditional is correct
  {
    pv6 RI = cmb[(size_t)i * FDIM + f];
    av0 += hi_f(RI.u1);
    av1 += lo_f(RI.u2);
    av2 += hi_f(RI.u2);
  }
  unsigned short* vlo = v_lin + (size_t)i * F3;
  vlo[f] = f2bf(av0);
  vlo[FDIM + f] = f2bf(av1);
  vlo[2 * FDIM + f] = f2bf(av2);
  s[(size_t)i * FDIM + f] += acc_s;
}

// ---------------- fused update (+ next-layer msg, or atom-energy readout) ----------------
__global__ __launch_bounds__(256) void upd_fused_kernel(
    float* __restrict__ s, const unsigned short* __restrict__ v_lin,
    pv6* __restrict__ cmb,
    const unsigned short* __restrict__ pU, const unsigned short* __restrict__ pV,
    const unsigned short* __restrict__ pW1, const float* __restrict__ b1,
    const unsigned short* __restrict__ pW2, const float* __restrict__ b2,
    int mode,
    const unsigned short* __restrict__ pMW1, const float* __restrict__ mb1,
    const unsigned short* __restrict__ pMW2, const float* __restrict__ mb2,
    const unsigned short* __restrict__ pRW1, const float* __restrict__ rb1,
    const float* __restrict__ rW2, const float* __restrict__ rb2,
    float* __restrict__ atom_e) {
  __shared__ bf16x8 vAf[3 * 4 * 64];
  __shared__ bf16x8 catA[8 * 64];
  __shared__ bf16x8 hA[4 * 64];
  __shared__ float red[4][16];
  int a0 = blockIdx.x * 16;
  int t = threadIdx.x;
  int lane = t & 63, w = t >> 6;
  {
    int l = t & 63, kb = (t >> 6) & 3;
    int m = l & 15, q = l >> 4;
#pragma unroll
    for (int rt = 0; rt < 3; rt++) {
      vAf[(rt * 4 + kb) * 64 + l] =
          *(const bf16x8*)(v_lin + (size_t)(a0 + m) * F3 + rt * FDIM + kb * 32 + q * 8);
    }
    const float* sp = s + (size_t)(a0 + m) * FDIM + kb * 32 + q * 8;
    bf16x8 c;
#pragma unroll
    for (int j = 0; j < 8; j++) c[j] = (short)f2bf(sp[j]);
    catA[kb * 64 + l] = c;
  }
  __syncthreads();
  f32x4 accU[3][2], accV[3][2];
#pragma unroll
  for (int rt = 0; rt < 3; rt++)
#pragma unroll
    for (int t2 = 0; t2 < 2; t2++)
#pragma unroll
      for (int r = 0; r < 4; r++) { accU[rt][t2][r] = 0.0f; accV[rt][t2][r] = 0.0f; }
  const bf16x8* Uf = (const bf16x8*)pU;
  const bf16x8* Vf = (const bf16x8*)pV;
#pragma unroll
  for (int kb = 0; kb < 4; kb++) {
    bf16x8 bu[2], bv[2];
#pragma unroll
    for (int t2 = 0; t2 < 2; t2++) {
      bu[t2] = Uf[(kb * 8 + 2 * w + t2) * 64 + lane];
      bv[t2] = Vf[(kb * 8 + 2 * w + t2) * 64 + lane];
    }
#pragma unroll
    for (int rt = 0; rt < 3; rt++) {
      bf16x8 a = vAf[(rt * 4 + kb) * 64 + lane];
#pragma unroll
      for (int t2 = 0; t2 < 2; t2++) {
        accU[rt][t2] = __builtin_amdgcn_mfma_f32_16x16x32_bf16(a, bu[t2], accU[rt][t2], 0, 0, 0);
        accV[rt][t2] = __builtin_amdgcn_mfma_f32_16x16x32_bf16(a, bv[t2], accV[rt][t2], 0, 0, 0);
      }
    }
  }
  short* cs = (short*)catA;
#pragma unroll
  for (int t2 = 0; t2 < 2; t2++) {
    int g = w * 32 + t2 * 16 + (lane & 15);
    int k = 128 + g;
    int kb = k >> 5, q = (k >> 3) & 3, j = k & 7;
#pragma unroll
    for (int r = 0; r < 4; r++) {
      int m = (lane >> 4) * 4 + r;
      float x0 = accV[0][t2][r], x1 = accV[1][t2][r], x2 = accV[2][t2][r];
      cs[(kb * 64 + q * 16 + m) * 8 + j] = (short)f2bf(sqrtf(x0 * x0 + x1 * x1 + x2 * x2 + EPS_F));
    }
  }
  __syncthreads();
  f32x4 accH[2];
#pragma unroll
  for (int t2 = 0; t2 < 2; t2++)
#pragma unroll
    for (int r = 0; r < 4; r++) accH[t2][r] = 0.0f;
  const bf16x8* W1f = (const bf16x8*)pW1;
#pragma unroll
  for (int kb = 0; kb < 8; kb++) {
    bf16x8 a = catA[kb * 64 + lane];
#pragma unroll
    for (int t2 = 0; t2 < 2; t2++) {
      bf16x8 b = W1f[(kb * 8 + 2 * w + t2) * 64 + lane];
      accH[t2] = __builtin_amdgcn_mfma_f32_16x16x32_bf16(a, b, accH[t2], 0, 0, 0);
    }
  }
  short* hs = (short*)hA;
#pragma unroll
  for (int t2 = 0; t2 < 2; t2++) {
    int n = w * 32 + t2 * 16 + (lane & 15);
    int kb = n >> 5, q = (n >> 3) & 3, j = n & 7;
    float bias = b1[n];
#pragma unroll
    for (int r = 0; r < 4; r++) {
      int m = (lane >> 4) * 4 + r;
      hs[(kb * 64 + q * 16 + m) * 8 + j] = (short)f2bf(silu_f(accH[t2][r] + bias));
    }
  }
  __syncthreads();
  f32x4 accA[3][2];
#pragma unroll
  for (int c3 = 0; c3 < 3; c3++)
#pragma unroll
    for (int t2 = 0; t2 < 2; t2++)
#pragma unroll
      for (int r = 0; r < 4; r++) accA[c3][t2][r] = 0.0f;
  const bf16x8* W2f = (const bf16x8*)pW2;
#pragma unroll
  for (int kb = 0; kb < 4; kb++) {
    bf16x8 a = hA[kb * 64 + lane];
#pragma unroll
    for (int c3 = 0; c3 < 3; c3++)
#pragma unroll
      for (int t2 = 0; t2 < 2; t2++) {
        bf16x8 b = W2f[(kb * 24 + c3 * 8 + 2 * w + t2) * 64 + lane];
        accA[c3][t2] = __builtin_amdgcn_mfma_f32_16x16x32_bf16(a, b, accA[c3][t2], 0, 0, 0);
      }
  }
  const short* vls = (const short*)vAf;  // v_old still live in LDS A-frag layout
  unsigned short v0keep[2][4];
#pragma unroll
  for (int t2 = 0; t2 < 2; t2++) {
    int g = w * 32 + t2 * 16 + (lane & 15);
    float bb0 = b2[g], bb1 = b2[FDIM + g], bb2 = b2[2 * FDIM + g];
    int kb = g >> 5, q = (g >> 3) & 3, j = g & 7;
#pragma unroll
    for (int r = 0; r < 4; r++) {
      int m = (lane >> 4) * 4 + r;
      int n = a0 + m;
      float a0v = accA[0][t2][r] + bb0;
      float a1v = accA[1][t2][r] + bb1;
      float a2v = accA[2][t2][r] + bb2;
      float dot = accU[0][t2][r] * accV[0][t2][r] + accU[1][t2][r] * accV[1][t2][r] +
                  accU[2][t2][r] * accV[2][t2][r];
      float s_new = s[(size_t)n * FDIM + g] + a1v * dot + a2v;
      if (mode == 0) {
        s[(size_t)n * FDIM + g] = s_new;
        float nv[3];
#pragma unroll
        for (int c = 0; c < 3; c++) {
          float vold = bf2f((unsigned short)vls[(((c * 4 + kb) * 64) + (q * 16 + m)) * 8 + j]);
          nv[c] = vold + a0v * accU[c][t2][r];
        }
        v0keep[t2][r] = f2bf(nv[0]);
        cmb[(size_t)n * FDIM + g].u2 = (unsigned)f2bf(nv[1]) | ((unsigned)f2bf(nv[2]) << 16);
      }
      cs[(kb * 64 + q * 16 + m) * 8 + j] = (short)f2bf(s_new);
    }
  }
  __syncthreads();
  if (mode == 0) {
    f32x4 accH2[2];
#pragma unroll
    for (int t2 = 0; t2 < 2; t2++)
#pragma unroll
      for (int r = 0; r < 4; r++) accH2[t2][r] = 0.0f;
    const bf16x8* MW1f = (const bf16x8*)pMW1;
#pragma unroll
    for (int kb = 0; kb < 4; kb++) {
      bf16x8 a = catA[kb * 64 + lane];
#pragma unroll
      for (int t2 = 0; t2 < 2; t2++) {
        bf16x8 b = MW1f[(kb * 8 + 2 * w + t2) * 64 + lane];
        accH2[t2] = __builtin_amdgcn_mfma_f32_16x16x32_bf16(a, b, accH2[t2], 0, 0, 0);
      }
    }
#pragma unroll
    for (int t2 = 0; t2 < 2; t2++) {
      int n = w * 32 + t2 * 16 + (lane & 15);
      int kb = n >> 5, q = (n >> 3) & 3, j = n & 7;
      float bias = mb1[n];
#pragma unroll
      for (int r = 0; r < 4; r++) {
        int m = (lane >> 4) * 4 + r;
        hs[(kb * 64 + q * 16 + m) * 8 + j] = (short)f2bf(silu_f(accH2[t2][r] + bias));
      }
    }
    __syncthreads();
    f32x4 accP[3][2];
#pragma unroll
    for (int c3 = 0; c3 < 3; c3++)
#pragma unroll
      for (int t2 = 0; t2 < 2; t2++)
#pragma unroll
        for (int r = 0; r < 4; r++) accP[c3][t2][r] = 0.0f;
    const bf16x8* MW2f = (const bf16x8*)pMW2;
#pragma unroll
    for (int kb = 0; kb < 4; kb++) {
      bf16x8 a = hA[kb * 64 + lane];
#pragma unroll
      for (int c3 = 0; c3 < 3; c3++)
#pragma unroll
        for (int t2 = 0; t2 < 2; t2++) {
          bf16x8 b = MW2f[(kb * 24 + c3 * 8 + 2 * w + t2) * 64 + lane];
          accP[c3][t2] = __builtin_amdgcn_mfma_f32_16x16x32_bf16(a, b, accP[c3][t2], 0, 0, 0);
        }
    }
#pragma unroll
    for (int t2 = 0; t2 < 2; t2++) {
      int g = (2 * w + t2) * 16 + (lane & 15);
      float bb0 = mb2[g], bb1 = mb2[FDIM + g], bb2v = mb2[2 * FDIM + g];
#pragma unroll
      for (int r = 0; r < 4; r++) {
        int m = (lane >> 4) * 4 + r;
        unsigned p0 = f2bf(accP[0][t2][r] + bb0);
        unsigned p1 = f2bf(accP[1][t2][r] + bb1);
        unsigned p2 = f2bf(accP[2][t2][r] + bb2v);
        pv6* rec = &cmb[(size_t)(a0 + m) * FDIM + g];
        rec->u0 = p0 | (p1 << 16);
        rec->u1 = p2 | ((unsigned)v0keep[t2][r] << 16);
      }
    }
  } else {
    f32x4 acc;
#pragma unroll
    for (int r = 0; r < 4; r++) acc[r] = 0.0f;
    const bf16x8* RW1f = (const bf16x8*)pRW1;
#pragma unroll
    for (int kb = 0; kb < 4; kb++) {
      bf16x8 a = catA[kb * 64 + lane];
      bf16x8 b = RW1f[(kb * 4 + w) * 64 + lane];
      acc = __builtin_amdgcn_mfma_f32_16x16x32_bf16(a, b, acc, 0, 0, 0);
    }
    int col = w * 16 + (lane & 15);
    float bias = rb1[col], w2v = rW2[col];
    float val[4];
#pragma unroll
    for (int r = 0; r < 4; r++) val[r] = silu_f(acc[r] + bias) * w2v;
#pragma unroll
    for (int off = 1; off < 16; off <<= 1)
#pragma unroll
      for (int r = 0; r < 4; r++) val[r] += __shfl_xor(val[r], off, 64);
    if ((lane & 15) == 0) {
#pragma unroll
      for (int r = 0; r < 4; r++) red[w][(lane >> 4) * 4 + r] = val[r];
    }
    __syncthreads();
    if (t < 16) {
      atom_e[a0 + t] = red[0][t] + red[1][t] + red[2][t] + red[3][t] + rb2[0];
    }
  }
}

// ---------------- molecule segment-sum: LDS partials, ~3 global atomics per block ----------------
__global__ __launch_bounds__(256) void mol_reduce_kernel(
    const float* __restrict__ atom_e, const int* __restrict__ mol_idx,
    float* __restrict__ out) {
  __shared__ float molsum[NMOLS];
  int t = threadIdx.x;
  if (t < NMOLS) molsum[t] = 0.0f;
  __syncthreads();
  int n = blockIdx.x * 256 + t;
  if (n < NA) atomicAdd(&molsum[mol_idx[n]], atom_e[n]);
  __syncthreads();
  if (t < NMOLS && molsum[t] != 0.0f) atomicAdd(&out[t], molsum[t]);
}

extern "C" void kernel_launch(void* const* d_in, const int* in_sizes, int n_in,
                              void* d_out, int out_size, void* d_ws, size_t ws_size,
                              hipStream_t stream) {
  const float* xyz = (const float*)d_in[0];
  const int* z = (const int*)d_in[1];
  const int* nbrs = (const int*)d_in[2];
  const int* mol = (const int*)d_in[3];
  const float* emb = (const float*)d_in[4];
  const float* msgW1 = (const float*)d_in[5];
  const float* msgb1 = (const float*)d_in[6];
  const float* msgW2 = (const float*)d_in[7];
  const float* msgb2 = (const float*)d_in[8];
  const float* distW = (const float*)d_in[9];
  const float* distb = (const float*)d_in[10];
  const float* updU = (const float*)d_in[11];
  const float* updV = (const float*)d_in[12];
  const float* updW1 = (const float*)d_in[13];
  const float* updb1 = (const float*)d_in[14];
  const float* updW2 = (const float*)d_in[15];
  const float* updb2 = (const float*)d_in[16];
  const float* rW1 = (const float*)d_in[17];
  const float* rb1 = (const float*)d_in[18];
  const float* rW2 = (const float*)d_in[19];
  const float* rb2 = (const float*)d_in[20];

  float* ws = (float*)d_ws;
  float* s = ws;      ws += (size_t)NA * FDIM;
  float* fcut = ws;   ws += (size_t)NE;
  float* unitv = ws;  ws += (size_t)NE * 3;
  float* atom_e = ws; ws += (size_t)NA;
  int* deg = (int*)ws;
  int* slot_e = deg + NA;
  int* slot_j = slot_e + NA * CAP;
  int* order = slot_j + NA * CAP;
  int* bins = order + NA;            // NBINS
  int* binoffs = bins + NBINS;       // NBINS
  int* bincur = binoffs + NBINS;     // NBINS
  unsigned short* pk = (unsigned short*)(((uintptr_t)(bincur + NBINS) + 15) & ~(uintptr_t)15);
  unsigned short* pMsgW1 = pk;                       // 49152
  unsigned short* pMsgW2 = pMsgW1 + 49152;           // 147456
  unsigned short* pUpdU  = pMsgW2 + 147456;          // 49152
  unsigned short* pUpdV  = pUpdU + 49152;            // 49152
  unsigned short* pUpdW1 = pUpdV + 49152;            // 98304
  unsigned short* pUpdW2 = pUpdW1 + 98304;           // 147456
  unsigned short* pRW1   = pUpdW2 + 147456;          // 8192
  unsigned short* pDW    = pRW1 + 8192;              // 3*12288
  unsigned short* rbf_bf = (unsigned short*)(((uintptr_t)(pDW + 36864) + 15) & ~(uintptr_t)15);
  unsigned short* after_rbf = rbf_bf + (size_t)NE * NRBF + 8;
  pv6* cmb = (pv6*)(((uintptr_t)after_rbf + 15) & ~(uintptr_t)15);           // NA*128 x 12B
  unsigned short* v_lin = (unsigned short*)(cmb + (size_t)NA * FDIM);        // NA*384

  hipMemsetAsync(deg, 0, NA * sizeof(int), stream);
  hipMemsetAsync(bins, 0, 3 * NBINS * sizeof(int), stream);
  hipMemsetAsync(d_out, 0, NMOLS * sizeof(float), stream);

  pack_all_kernel<<<(585728 + 255) / 256, 256, 0, stream>>>(
      msgW1, msgW2, updU, updV, updW1, updW2, rW1, distW, distb, pMsgW1);
  geom_build_kernel<<<NE / 256, 256, 0, stream>>>(xyz, nbrs, unitv, rbf_bf, fcut,
                                                  deg, slot_e, slot_j);
  hist_kernel<<<(NA + 255) / 256, 256, 0, stream>>>(deg, bins);
  scan_bins_kernel<<<1, 128, 0, stream>>>(bins, binoffs);
  scatter_kernel<<<(NA + 255) / 256, 256, 0, stream>>>(deg, binoffs, bincur, order);
  msg0_mfma_kernel<<<NA / 16, 256, 0, stream>>>(emb, z, s, pMsgW1, msgb1, pMsgW2, msgb2, cmb);

  for (int l = 0; l < NLAYERS; l++) {
    edge_kernel<<<NA, 128, 0, stream>>>(cmb, v_lin, s,
                                        pDW + (size_t)l * 12288,
                                        deg, slot_e, slot_j, rbf_bf, fcut, unitv, order);
    int mode = (l == NLAYERS - 1) ? 1 : 0;
    int lnext = (l + 1 < NLAYERS) ? l + 1 : 0;
    upd_fused_kernel<<<NA / 16, 256, 0, stream>>>(
        s, v_lin, cmb, pUpdU + (size_t)l * 16384, pUpdV + (size_t)l * 16384,
        pUpdW1 + (size_t)l * 32768, updb1 + (size_t)l * FDIM,
        pUpdW2 + (size_t)l * 49152, updb2 + (size_t)l * F3,
        mode,
        pMsgW1 + (size_t)lnext * 16384, msgb1 + (size_t)lnext * FDIM,
        pMsgW2 + (size_t)lnext * 49152, msgb2 + (size_t)lnext * F3,
        pRW1, rb1, rW2, rb2, atom_e);
  }
  mol_reduce_kernel<<<(NA + 255) / 256, 256, 0, stream>>>(atom_e, mol, (float*)d_out);
}

// Round 16
// 303.259 us; speedup vs baseline: 1.2152x; 1.2152x over previous
//
#include <hip/hip_runtime.h>
#include <hip/hip_bf16.h>
#include <math.h>

#define NA 10000
#define NE 256000
#define FDIM 128
#define F3 384
#define NRBF 20
#define NLAYERS 3
#define NMOLS 100
#define CAP 96
#define WROW 388  // padded w_lds row (bf16): conflict-free MFMA-C transpose (verified R6)
#define CUTOFF_F 5.0f
#define EPS_F 1e-8f
#define PI_F 3.14159265358979323846f

typedef __attribute__((ext_vector_type(8))) short bf16x8;
typedef __attribute__((ext_vector_type(4))) float f32x4;

// 12-byte fused record: {phi0, phi1, phi2, v0, v1, v2} bf16
struct pv6 { unsigned int u0, u1, u2; };

__device__ __forceinline__ float silu_f(float x) { return x / (1.0f + __expf(-x)); }

__device__ __forceinline__ unsigned short f2bf(float x) {
  unsigned u = __float_as_uint(x);
  return (unsigned short)((u + 0x7FFFu + ((u >> 16) & 1u)) >> 16);
}
__device__ __forceinline__ float bf2f(unsigned short u) {
  return __uint_as_float(((unsigned)u) << 16);
}
__device__ __forceinline__ float lo_f(unsigned int u) { return bf2f((unsigned short)(u & 0xFFFFu)); }
__device__ __forceinline__ float hi_f(unsigned int u) { return bf2f((unsigned short)(u >> 16)); }

// ---------------- fused geometry + bucket build (rbf: bf16, fcut pre-multiplied) ----------------
__global__ __launch_bounds__(256) void geom_build_kernel(
    const float* __restrict__ xyz, const int* __restrict__ nbrs,
    float* __restrict__ unitv, unsigned short* __restrict__ rbf_bf,
    float* __restrict__ fcut,
    int* __restrict__ deg, int* __restrict__ slot_e, int* __restrict__ slot_j) {
  int e = blockIdx.x * 256 + threadIdx.x;
  if (e >= NE) return;
  int i = nbrs[2 * e + 0], j = nbrs[2 * e + 1];
  float rx = xyz[3 * j + 0] - xyz[3 * i + 0];
  float ry = xyz[3 * j + 1] - xyz[3 * i + 1];
  float rz = xyz[3 * j + 2] - xyz[3 * i + 2];
  float d = sqrtf(rx * rx + ry * ry + rz * rz + EPS_F);
  if (d >= CUTOFF_F) return;
  float invd = 1.0f / d;
  float fc = 0.5f * (__cosf(PI_F * d / CUTOFF_F) + 1.0f);
  unitv[3 * e + 0] = rx * invd;
  unitv[3 * e + 1] = ry * invd;
  unitv[3 * e + 2] = rz * invd;
  fcut[e] = fc;
  float base = PI_F * d / CUTOFF_F;
  float sc = invd * fc;
#pragma unroll
  for (int k = 0; k < NRBF; k++)
    rbf_bf[(size_t)e * NRBF + k] = f2bf(__sinf((float)(k + 1) * base) * sc);
  int pos = atomicAdd(&deg[i], 1);
  if (pos < CAP) {
    slot_e[i * CAP + pos] = e;
    slot_j[i * CAP + pos] = j;
  }
}

// ---------------- single fused weight pack -> B-fragment bf16 layout ----------------
__device__ __forceinline__ void pack_one(const float* __restrict__ src,
                                         unsigned short* __restrict__ dst,
                                         int loc, int per, int N) {
  int lay = loc / per;
  int kn = loc - lay * per;
  int k = kn / N, n = kn - k * N;
  int kb = k >> 5, q = (k >> 3) & 3, j = k & 7, nt = n >> 4, c = n & 15;
  int NT = N >> 4;
  dst[(size_t)lay * per + (((kb * NT + nt) * 64 + (q * 16 + c)) * 8 + j)] = f2bf(src[loc]);
}

// dist_W padded pack: K=32 (rows 0..19 = dW, row 20 = db, rest 0), N=384
__device__ __forceinline__ void pack_dw(const float* __restrict__ dW,
                                        const float* __restrict__ db,
                                        unsigned short* __restrict__ dst, int loc) {
  int lay = loc / 12288;
  int kn = loc - lay * 12288;
  int k = kn / 384, n = kn - k * 384;
  float val = 0.0f;
  if (k < NRBF) val = dW[lay * NRBF * 384 + k * 384 + n];
  else if (k == NRBF) val = db[lay * 384 + n];
  int q = (k >> 3) & 3, j = k & 7, nt = n >> 4, c = n & 15;
  dst[(size_t)lay * 12288 + ((nt * 64 + (q * 16 + c)) * 8 + j)] = f2bf(val);
}

__global__ __launch_bounds__(256) void pack_all_kernel(
    const float* __restrict__ msgW1, const float* __restrict__ msgW2,
    const float* __restrict__ updU, const float* __restrict__ updV,
    const float* __restrict__ updW1, const float* __restrict__ updW2,
    const float* __restrict__ rW1, const float* __restrict__ distW,
    const float* __restrict__ distb, unsigned short* __restrict__ dst) {
  int t = blockIdx.x * 256 + threadIdx.x;
  if (t < 49152) pack_one(msgW1, dst, t, 16384, 128);
  else if (t < 196608) pack_one(msgW2, dst + 49152, t - 49152, 49152, 384);
  else if (t < 245760) pack_one(updU, dst + 196608, t - 196608, 16384, 128);
  else if (t < 294912) pack_one(updV, dst + 245760, t - 245760, 16384, 128);
  else if (t < 393216) pack_one(updW1, dst + 294912, t - 294912, 32768, 128);
  else if (t < 540672) pack_one(updW2, dst + 393216, t - 393216, 49152, 384);
  else if (t < 548864) pack_one(rW1, dst + 540672, t - 540672, 8192, 64);
  else if (t < 585728) pack_dw(distW, distb, dst + 548864, t - 548864);
}

// ---------------- layer-0 message MLP (fused s = emb[z] init); writes pv6 {phi, v=0} ----------------
__global__ __launch_bounds__(256) void msg0_mfma_kernel(
    const float* __restrict__ emb, const int* __restrict__ z, float* __restrict__ s_out,
    const unsigned short* __restrict__ pW1, const float* __restrict__ b1,
    const unsigned short* __restrict__ pW2, const float* __restrict__ b2,
    pv6* __restrict__ cmb) {
  __shared__ bf16x8 sA[4 * 64];
  __shared__ bf16x8 hA[4 * 64];
  int a0 = blockIdx.x * 16;
  int t = threadIdx.x;
  int lane = t & 63, w = t >> 6;
  {
    int kb = t >> 6, l = t & 63;
    int m = l & 15, q = l >> 4;
    int zi = z[a0 + m];
    const float* sp = emb + (size_t)zi * FDIM + kb * 32 + q * 8;
    float* so = s_out + (size_t)(a0 + m) * FDIM + kb * 32 + q * 8;
    bf16x8 c;
#pragma unroll
    for (int j = 0; j < 8; j++) {
      float v = sp[j];
      so[j] = v;
      c[j] = (short)f2bf(v);
    }
    sA[kb * 64 + l] = c;
  }
  __syncthreads();
  f32x4 accH[2];
#pragma unroll
  for (int t2 = 0; t2 < 2; t2++)
#pragma unroll
    for (int r = 0; r < 4; r++) accH[t2][r] = 0.0f;
  const bf16x8* W1f = (const bf16x8*)pW1;
#pragma unroll
  for (int kb = 0; kb < 4; kb++) {
    bf16x8 a = sA[kb * 64 + lane];
#pragma unroll
    for (int t2 = 0; t2 < 2; t2++) {
      bf16x8 b = W1f[(kb * 8 + 2 * w + t2) * 64 + lane];
      accH[t2] = __builtin_amdgcn_mfma_f32_16x16x32_bf16(a, b, accH[t2], 0, 0, 0);
    }
  }
  short* hs = (short*)hA;
#pragma unroll
  for (int t2 = 0; t2 < 2; t2++) {
    int n = w * 32 + t2 * 16 + (lane & 15);
    int kb = n >> 5, q = (n >> 3) & 3, j = n & 7;
    float bias = b1[n];
#pragma unroll
    for (int r = 0; r < 4; r++) {
      int m = (lane >> 4) * 4 + r;
      hs[(kb * 64 + q * 16 + m) * 8 + j] = (short)f2bf(silu_f(accH[t2][r] + bias));
    }
  }
  __syncthreads();
  f32x4 accP[3][2];
#pragma unroll
  for (int c3 = 0; c3 < 3; c3++)
#pragma unroll
    for (int t2 = 0; t2 < 2; t2++)
#pragma unroll
      for (int r = 0; r < 4; r++) accP[c3][t2][r] = 0.0f;
  const bf16x8* W2f = (const bf16x8*)pW2;
#pragma unroll
  for (int kb = 0; kb < 4; kb++) {
    bf16x8 a = hA[kb * 64 + lane];
#pragma unroll
    for (int c3 = 0; c3 < 3; c3++)
#pragma unroll
      for (int t2 = 0; t2 < 2; t2++) {
        bf16x8 b = W2f[(kb * 24 + c3 * 8 + 2 * w + t2) * 64 + lane];
        accP[c3][t2] = __builtin_amdgcn_mfma_f32_16x16x32_bf16(a, b, accP[c3][t2], 0, 0, 0);
      }
  }
#pragma unroll
  for (int t2 = 0; t2 < 2; t2++) {
    int g = (2 * w + t2) * 16 + (lane & 15);
    float bb0 = b2[g], bb1 = b2[FDIM + g], bb2 = b2[2 * FDIM + g];
#pragma unroll
    for (int r = 0; r < 4; r++) {
      int m = (lane >> 4) * 4 + r;
      unsigned p0 = f2bf(accP[0][t2][r] + bb0);
      unsigned p1 = f2bf(accP[1][t2][r] + bb1);
      unsigned p2 = f2bf(accP[2][t2][r] + bb2);
      pv6 rec;
      rec.u0 = p0 | (p1 << 16);
      rec.u1 = p2;
      rec.u2 = 0;
      cmb[(size_t)(a0 + m) * FDIM + g] = rec;
    }
  }
}

// ---------------- edge aggregation: 128 thr, unconditional 12B pv6 gather ----------------
__global__ __launch_bounds__(128) void edge_kernel(
    const pv6* __restrict__ cmb, unsigned short* __restrict__ v_lin,
    float* __restrict__ s, const unsigned short* __restrict__ pDW,
    const int* __restrict__ deg, const int* __restrict__ slot_e,
    const int* __restrict__ slot_j, const unsigned short* __restrict__ rbf_bf,
    const float* __restrict__ fcut, const float* __restrict__ unitv) {
  __shared__ bf16x8 aLDS[64];
  __shared__ unsigned short w_lds[16][WROW];
  __shared__ float l_u[16][3];
  __shared__ int l_j[16];
  int i = blockIdx.x;
  int t = threadIdx.x;
  int f = t;
  int lane = t & 63, w = t >> 6;
  int cnt = deg[i];
  if (cnt > CAP) cnt = CAP;
  int base = i * CAP;
  float acc_s = 0.f, av0 = 0.f, av1 = 0.f, av2 = 0.f;
  const bf16x8* Bf = (const bf16x8*)pDW;
  for (int c0 = 0; c0 < cnt; c0 += 16) {
    int ccnt = cnt - c0;
    if (ccnt > 16) ccnt = 16;
    __syncthreads();  // prev chunk's LDS reads done before overwrite
    if (t < 64) {
      int m = t & 15, q = t >> 4;
      bf16x8 a;
#pragma unroll
      for (int j = 0; j < 8; j++) a[j] = 0;
      int p = c0 + m;
      if (p < cnt) {
        int e = slot_e[base + p];
        const unsigned short* rb = rbf_bf + (size_t)e * NRBF;
#pragma unroll
        for (int j = 0; j < 8; j++) {
          int k = q * 8 + j;
          if (k < NRBF) a[j] = (short)rb[k];
          else if (k == NRBF) a[j] = (short)f2bf(fcut[e]);
        }
      }
      aLDS[t] = a;
    } else if (t < 80) {
      int idx = t - 64;
      int p = c0 + idx;
      if (p < cnt) {
        int e = slot_e[base + p];
        l_j[idx] = slot_j[base + p];
        l_u[idx][0] = unitv[3 * e + 0];
        l_u[idx][1] = unitv[3 * e + 1];
        l_u[idx][2] = unitv[3 * e + 2];
      }
    }
    __syncthreads();
    {
      bf16x8 a = aLDS[lane];
      int n0 = lane & 15, m0 = (lane >> 4) * 4;
#pragma unroll
      for (int tt = 0; tt < 12; tt++) {
        int nt = 12 * w + tt;
        f32x4 acc;
#pragma unroll
        for (int r = 0; r < 4; r++) acc[r] = 0.0f;
        acc = __builtin_amdgcn_mfma_f32_16x16x32_bf16(a, Bf[nt * 64 + lane], acc, 0, 0, 0);
        int n = nt * 16 + n0;
#pragma unroll
        for (int r = 0; r < 4; r++) w_lds[m0 + r][n] = f2bf(acc[r]);
      }
    }
    __syncthreads();
    int pp = 0;
    for (; pp + 2 <= ccnt; pp += 2) {
      int j0 = l_j[pp], j1 = l_j[pp + 1];
      pv6 R0 = cmb[(size_t)j0 * FDIM + f];
      pv6 R1 = cmb[(size_t)j1 * FDIM + f];
      float p00 = lo_f(R0.u0), p01 = hi_f(R0.u0), p02 = lo_f(R0.u1);
      float v00 = hi_f(R0.u1), v01 = lo_f(R0.u2), v02 = hi_f(R0.u2);
      float p10 = lo_f(R1.u0), p11 = hi_f(R1.u0), p12 = lo_f(R1.u1);
      float v10 = hi_f(R1.u1), v11 = lo_f(R1.u2), v12 = hi_f(R1.u2);
      float w00 = bf2f(w_lds[pp][f]), w01 = bf2f(w_lds[pp][FDIM + f]),
            w02 = bf2f(w_lds[pp][2 * FDIM + f]);
      float w10 = bf2f(w_lds[pp + 1][f]), w11 = bf2f(w_lds[pp + 1][FDIM + f]),
            w12 = bf2f(w_lds[pp + 1][2 * FDIM + f]);
      acc_s += p00 * w00 + p10 * w10;
      float i01 = p01 * w01, i02 = p02 * w02, i11 = p11 * w11, i12 = p12 * w12;
      av0 += i01 * v00 + i02 * l_u[pp][0] + i11 * v10 + i12 * l_u[pp + 1][0];
      av1 += i01 * v01 + i02 * l_u[pp][1] + i11 * v11 + i12 * l_u[pp + 1][1];
      av2 += i01 * v02 + i02 * l_u[pp][2] + i11 * v12 + i12 * l_u[pp + 1][2];
    }
    if (pp < ccnt) {
      int j0 = l_j[pp];
      pv6 R0 = cmb[(size_t)j0 * FDIM + f];
      float p00 = lo_f(R0.u0), p01 = hi_f(R0.u0), p02 = lo_f(R0.u1);
      float v00 = hi_f(R0.u1), v01 = lo_f(R0.u2), v02 = hi_f(R0.u2);
      float w00 = bf2f(w_lds[pp][f]), w01 = bf2f(w_lds[pp][FDIM + f]),
            w02 = bf2f(w_lds[pp][2 * FDIM + f]);
      acc_s += p00 * w00;
      float i01 = p01 * w01, i02 = p02 * w02;
      av0 += i01 * v00 + i02 * l_u[pp][0];
      av1 += i01 * v01 + i02 * l_u[pp][1];
      av2 += i01 * v02 + i02 * l_u[pp][2];
    }
  }
  // own-atom v add: cmb v-halves are 0 for layer 0, so unconditional is correct
  {
    pv6 RI = cmb[(size_t)i * FDIM + f];
    av0 += hi_f(RI.u1);
    av1 += lo_f(RI.u2);
    av2 += hi_f(RI.u2);
  }
  unsigned short* vlo = v_lin + (size_t)i * F3;
  vlo[f] = f2bf(av0);
  vlo[FDIM + f] = f2bf(av1);
  vlo[2 * FDIM + f] = f2bf(av2);
  s[(size_t)i * FDIM + f] += acc_s;
}

// ---------------- fused update (+ next-layer msg, or atom-energy readout) ----------------
// v_old re-read from vAf LDS (still live); u2 stored in s-epilogue; v0 kept in regs for msg epilogue.
__global__ __launch_bounds__(256) void upd_fused_kernel(
    float* __restrict__ s, const unsigned short* __restrict__ v_lin,
    pv6* __restrict__ cmb,
    const unsigned short* __restrict__ pU, const unsigned short* __restrict__ pV,
    const unsigned short* __restrict__ pW1, const float* __restrict__ b1,
    const unsigned short* __restrict__ pW2, const float* __restrict__ b2,
    int mode,
    const unsigned short* __restrict__ pMW1, const float* __restrict__ mb1,
    const unsigned short* __restrict__ pMW2, const float* __restrict__ mb2,
    const unsigned short* __restrict__ pRW1, const float* __restrict__ rb1,
    const float* __restrict__ rW2, const float* __restrict__ rb2,
    float* __restrict__ atom_e) {
  __shared__ bf16x8 vAf[3 * 4 * 64];
  __shared__ bf16x8 catA[8 * 64];
  __shared__ bf16x8 hA[4 * 64];
  __shared__ float red[4][16];
  int a0 = blockIdx.x * 16;
  int t = threadIdx.x;
  int lane = t & 63, w = t >> 6;
  {
    int l = t & 63, kb = (t >> 6) & 3;
    int m = l & 15, q = l >> 4;
#pragma unroll
    for (int rt = 0; rt < 3; rt++) {
      vAf[(rt * 4 + kb) * 64 + l] =
          *(const bf16x8*)(v_lin + (size_t)(a0 + m) * F3 + rt * FDIM + kb * 32 + q * 8);
    }
    const float* sp = s + (size_t)(a0 + m) * FDIM + kb * 32 + q * 8;
    bf16x8 c;
#pragma unroll
    for (int j = 0; j < 8; j++) c[j] = (short)f2bf(sp[j]);
    catA[kb * 64 + l] = c;
  }
  __syncthreads();
  f32x4 accU[3][2], accV[3][2];
#pragma unroll
  for (int rt = 0; rt < 3; rt++)
#pragma unroll
    for (int t2 = 0; t2 < 2; t2++)
#pragma unroll
      for (int r = 0; r < 4; r++) { accU[rt][t2][r] = 0.0f; accV[rt][t2][r] = 0.0f; }
  const bf16x8* Uf = (const bf16x8*)pU;
  const bf16x8* Vf = (const bf16x8*)pV;
#pragma unroll
  for (int kb = 0; kb < 4; kb++) {
    bf16x8 bu[2], bv[2];
#pragma unroll
    for (int t2 = 0; t2 < 2; t2++) {
      bu[t2] = Uf[(kb * 8 + 2 * w + t2) * 64 + lane];
      bv[t2] = Vf[(kb * 8 + 2 * w + t2) * 64 + lane];
    }
#pragma unroll
    for (int rt = 0; rt < 3; rt++) {
      bf16x8 a = vAf[(rt * 4 + kb) * 64 + lane];
#pragma unroll
      for (int t2 = 0; t2 < 2; t2++) {
        accU[rt][t2] = __builtin_amdgcn_mfma_f32_16x16x32_bf16(a, bu[t2], accU[rt][t2], 0, 0, 0);
        accV[rt][t2] = __builtin_amdgcn_mfma_f32_16x16x32_bf16(a, bv[t2], accV[rt][t2], 0, 0, 0);
      }
    }
  }
  short* cs = (short*)catA;
#pragma unroll
  for (int t2 = 0; t2 < 2; t2++) {
    int g = w * 32 + t2 * 16 + (lane & 15);
    int k = 128 + g;
    int kb = k >> 5, q = (k >> 3) & 3, j = k & 7;
#pragma unroll
    for (int r = 0; r < 4; r++) {
      int m = (lane >> 4) * 4 + r;
      float x0 = accV[0][t2][r], x1 = accV[1][t2][r], x2 = accV[2][t2][r];
      cs[(kb * 64 + q * 16 + m) * 8 + j] = (short)f2bf(sqrtf(x0 * x0 + x1 * x1 + x2 * x2 + EPS_F));
    }
  }
  __syncthreads();
  f32x4 accH[2];
#pragma unroll
  for (int t2 = 0; t2 < 2; t2++)
#pragma unroll
    for (int r = 0; r < 4; r++) accH[t2][r] = 0.0f;
  const bf16x8* W1f = (const bf16x8*)pW1;
#pragma unroll
  for (int kb = 0; kb < 8; kb++) {
    bf16x8 a = catA[kb * 64 + lane];
#pragma unroll
    for (int t2 = 0; t2 < 2; t2++) {
      bf16x8 b = W1f[(kb * 8 + 2 * w + t2) * 64 + lane];
      accH[t2] = __builtin_amdgcn_mfma_f32_16x16x32_bf16(a, b, accH[t2], 0, 0, 0);
    }
  }
  short* hs = (short*)hA;
#pragma unroll
  for (int t2 = 0; t2 < 2; t2++) {
    int n = w * 32 + t2 * 16 + (lane & 15);
    int kb = n >> 5, q = (n >> 3) & 3, j = n & 7;
    float bias = b1[n];
#pragma unroll
    for (int r = 0; r < 4; r++) {
      int m = (lane >> 4) * 4 + r;
      hs[(kb * 64 + q * 16 + m) * 8 + j] = (short)f2bf(silu_f(accH[t2][r] + bias));
    }
  }
  __syncthreads();
  f32x4 accA[3][2];
#pragma unroll
  for (int c3 = 0; c3 < 3; c3++)
#pragma unroll
    for (int t2 = 0; t2 < 2; t2++)
#pragma unroll
      for (int r = 0; r < 4; r++) accA[c3][t2][r] = 0.0f;
  const bf16x8* W2f = (const bf16x8*)pW2;
#pragma unroll
  for (int kb = 0; kb < 4; kb++) {
    bf16x8 a = hA[kb * 64 + lane];
#pragma unroll
    for (int c3 = 0; c3 < 3; c3++)
#pragma unroll
      for (int t2 = 0; t2 < 2; t2++) {
        bf16x8 b = W2f[(kb * 24 + c3 * 8 + 2 * w + t2) * 64 + lane];
        accA[c3][t2] = __builtin_amdgcn_mfma_f32_16x16x32_bf16(a, b, accA[c3][t2], 0, 0, 0);
      }
  }
  const short* vls = (const short*)vAf;  // v_old still live in LDS A-frag layout
  unsigned short v0keep[2][4];
#pragma unroll
  for (int t2 = 0; t2 < 2; t2++) {
    int g = w * 32 + t2 * 16 + (lane & 15);
    float bb0 = b2[g], bb1 = b2[FDIM + g], bb2 = b2[2 * FDIM + g];
    int kb = g >> 5, q = (g >> 3) & 3, j = g & 7;
#pragma unroll
    for (int r = 0; r < 4; r++) {
      int m = (lane >> 4) * 4 + r;
      int n = a0 + m;
      float a0v = accA[0][t2][r] + bb0;
      float a1v = accA[1][t2][r] + bb1;
      float a2v = accA[2][t2][r] + bb2;
      float dot = accU[0][t2][r] * accV[0][t2][r] + accU[1][t2][r] * accV[1][t2][r] +
                  accU[2][t2][r] * accV[2][t2][r];
      float s_new = s[(size_t)n * FDIM + g] + a1v * dot + a2v;
      if (mode == 0) {
        s[(size_t)n * FDIM + g] = s_new;
        float nv[3];
#pragma unroll
        for (int c = 0; c < 3; c++) {
          float vold = bf2f((unsigned short)vls[(((c * 4 + kb) * 64) + (q * 16 + m)) * 8 + j]);
          nv[c] = vold + a0v * accU[c][t2][r];
        }
        v0keep[t2][r] = f2bf(nv[0]);
        cmb[(size_t)n * FDIM + g].u2 = (unsigned)f2bf(nv[1]) | ((unsigned)f2bf(nv[2]) << 16);
      }
      cs[(kb * 64 + q * 16 + m) * 8 + j] = (short)f2bf(s_new);
    }
  }
  __syncthreads();
  if (mode == 0) {
    f32x4 accH2[2];
#pragma unroll
    for (int t2 = 0; t2 < 2; t2++)
#pragma unroll
      for (int r = 0; r < 4; r++) accH2[t2][r] = 0.0f;
    const bf16x8* MW1f = (const bf16x8*)pMW1;
#pragma unroll
    for (int kb = 0; kb < 4; kb++) {
      bf16x8 a = catA[kb * 64 + lane];
#pragma unroll
      for (int t2 = 0; t2 < 2; t2++) {
        bf16x8 b = MW1f[(kb * 8 + 2 * w + t2) * 64 + lane];
        accH2[t2] = __builtin_amdgcn_mfma_f32_16x16x32_bf16(a, b, accH2[t2], 0, 0, 0);
      }
    }
#pragma unroll
    for (int t2 = 0; t2 < 2; t2++) {
      int n = w * 32 + t2 * 16 + (lane & 15);
      int kb = n >> 5, q = (n >> 3) & 3, j = n & 7;
      float bias = mb1[n];
#pragma unroll
      for (int r = 0; r < 4; r++) {
        int m = (lane >> 4) * 4 + r;
        hs[(kb * 64 + q * 16 + m) * 8 + j] = (short)f2bf(silu_f(accH2[t2][r] + bias));
      }
    }
    __syncthreads();
    f32x4 accP[3][2];
#pragma unroll
    for (int c3 = 0; c3 < 3; c3++)
#pragma unroll
      for (int t2 = 0; t2 < 2; t2++)
#pragma unroll
        for (int r = 0; r < 4; r++) accP[c3][t2][r] = 0.0f;
    const bf16x8* MW2f = (const bf16x8*)pMW2;
#pragma unroll
    for (int kb = 0; kb < 4; kb++) {
      bf16x8 a = hA[kb * 64 + lane];
#pragma unroll
      for (int c3 = 0; c3 < 3; c3++)
#pragma unroll
        for (int t2 = 0; t2 < 2; t2++) {
          bf16x8 b = MW2f[(kb * 24 + c3 * 8 + 2 * w + t2) * 64 + lane];
          accP[c3][t2] = __builtin_amdgcn_mfma_f32_16x16x32_bf16(a, b, accP[c3][t2], 0, 0, 0);
        }
    }
#pragma unroll
    for (int t2 = 0; t2 < 2; t2++) {
      int g = (2 * w + t2) * 16 + (lane & 15);
      float bb0 = mb2[g], bb1 = mb2[FDIM + g], bb2v = mb2[2 * FDIM + g];
#pragma unroll
      for (int r = 0; r < 4; r++) {
        int m = (lane >> 4) * 4 + r;
        unsigned p0 = f2bf(accP[0][t2][r] + bb0);
        unsigned p1 = f2bf(accP[1][t2][r] + bb1);
        unsigned p2 = f2bf(accP[2][t2][r] + bb2v);
        pv6* rec = &cmb[(size_t)(a0 + m) * FDIM + g];
        rec->u0 = p0 | (p1 << 16);
        rec->u1 = p2 | ((unsigned)v0keep[t2][r] << 16);
      }
    }
  } else {
    f32x4 acc;
#pragma unroll
    for (int r = 0; r < 4; r++) acc[r] = 0.0f;
    const bf16x8* RW1f = (const bf16x8*)pRW1;
#pragma unroll
    for (int kb = 0; kb < 4; kb++) {
      bf16x8 a = catA[kb * 64 + lane];
      bf16x8 b = RW1f[(kb * 4 + w) * 64 + lane];
      acc = __builtin_amdgcn_mfma_f32_16x16x32_bf16(a, b, acc, 0, 0, 0);
    }
    int col = w * 16 + (lane & 15);
    float bias = rb1[col], w2v = rW2[col];
    float val[4];
#pragma unroll
    for (int r = 0; r < 4; r++) val[r] = silu_f(acc[r] + bias) * w2v;
#pragma unroll
    for (int off = 1; off < 16; off <<= 1)
#pragma unroll
      for (int r = 0; r < 4; r++) val[r] += __shfl_xor(val[r], off, 64);
    if ((lane & 15) == 0) {
#pragma unroll
      for (int r = 0; r < 4; r++) red[w][(lane >> 4) * 4 + r] = val[r];
    }
    __syncthreads();
    if (t < 16) {
      atom_e[a0 + t] = red[0][t] + red[1][t] + red[2][t] + red[3][t] + rb2[0];
    }
  }
}

// ---------------- molecule segment-sum: LDS partials, ~3 global atomics per block ----------------
__global__ __launch_bounds__(256) void mol_reduce_kernel(
    const float* __restrict__ atom_e, const int* __restrict__ mol_idx,
    float* __restrict__ out) {
  __shared__ float molsum[NMOLS];
  int t = threadIdx.x;
  if (t < NMOLS) molsum[t] = 0.0f;
  __syncthreads();
  int n = blockIdx.x * 256 + t;
  if (n < NA) atomicAdd(&molsum[mol_idx[n]], atom_e[n]);
  __syncthreads();
  if (t < NMOLS && molsum[t] != 0.0f) atomicAdd(&out[t], molsum[t]);
}

extern "C" void kernel_launch(void* const* d_in, const int* in_sizes, int n_in,
                              void* d_out, int out_size, void* d_ws, size_t ws_size,
                              hipStream_t stream) {
  const float* xyz = (const float*)d_in[0];
  const int* z = (const int*)d_in[1];
  const int* nbrs = (const int*)d_in[2];
  const int* mol = (const int*)d_in[3];
  const float* emb = (const float*)d_in[4];
  const float* msgW1 = (const float*)d_in[5];
  const float* msgb1 = (const float*)d_in[6];
  const float* msgW2 = (const float*)d_in[7];
  const float* msgb2 = (const float*)d_in[8];
  const float* distW = (const float*)d_in[9];
  const float* distb = (const float*)d_in[10];
  const float* updU = (const float*)d_in[11];
  const float* updV = (const float*)d_in[12];
  const float* updW1 = (const float*)d_in[13];
  const float* updb1 = (const float*)d_in[14];
  const float* updW2 = (const float*)d_in[15];
  const float* updb2 = (const float*)d_in[16];
  const float* rW1 = (const float*)d_in[17];
  const float* rb1 = (const float*)d_in[18];
  const float* rW2 = (const float*)d_in[19];
  const float* rb2 = (const float*)d_in[20];

  float* ws = (float*)d_ws;
  float* s = ws;      ws += (size_t)NA * FDIM;
  float* fcut = ws;   ws += (size_t)NE;
  float* unitv = ws;  ws += (size_t)NE * 3;
  float* atom_e = ws; ws += (size_t)NA;
  int* deg = (int*)ws;
  int* slot_e = deg + NA;
  int* slot_j = slot_e + NA * CAP;
  unsigned short* pk = (unsigned short*)(((uintptr_t)(slot_j + NA * CAP) + 15) & ~(uintptr_t)15);
  unsigned short* pMsgW1 = pk;                       // 49152
  unsigned short* pMsgW2 = pMsgW1 + 49152;           // 147456
  unsigned short* pUpdU  = pMsgW2 + 147456;          // 49152
  unsigned short* pUpdV  = pUpdU + 49152;            // 49152
  unsigned short* pUpdW1 = pUpdV + 49152;            // 98304
  unsigned short* pUpdW2 = pUpdW1 + 98304;           // 147456
  unsigned short* pRW1   = pUpdW2 + 147456;          // 8192
  unsigned short* pDW    = pRW1 + 8192;              // 3*12288
  unsigned short* rbf_bf = (unsigned short*)(((uintptr_t)(pDW + 36864) + 15) & ~(uintptr_t)15);
  unsigned short* after_rbf = rbf_bf + (size_t)NE * NRBF + 8;
  pv6* cmb = (pv6*)(((uintptr_t)after_rbf + 15) & ~(uintptr_t)15);           // NA*128 x 12B
  unsigned short* v_lin = (unsigned short*)(cmb + (size_t)NA * FDIM);        // NA*384

  hipMemsetAsync(deg, 0, NA * sizeof(int), stream);
  hipMemsetAsync(d_out, 0, NMOLS * sizeof(float), stream);

  pack_all_kernel<<<(585728 + 255) / 256, 256, 0, stream>>>(
      msgW1, msgW2, updU, updV, updW1, updW2, rW1, distW, distb, pMsgW1);
  geom_build_kernel<<<NE / 256, 256, 0, stream>>>(xyz, nbrs, unitv, rbf_bf, fcut,
                                                  deg, slot_e, slot_j);
  msg0_mfma_kernel<<<NA / 16, 256, 0, stream>>>(emb, z, s, pMsgW1, msgb1, pMsgW2, msgb2, cmb);

  for (int l = 0; l < NLAYERS; l++) {
    edge_kernel<<<NA, 128, 0, stream>>>(cmb, v_lin, s,
                                        pDW + (size_t)l * 12288,
                                        deg, slot_e, slot_j, rbf_bf, fcut, unitv);
    int mode = (l == NLAYERS - 1) ? 1 : 0;
    int lnext = (l + 1 < NLAYERS) ? l + 1 : 0;
    upd_fused_kernel<<<NA / 16, 256, 0, stream>>>(
        s, v_lin, cmb, pUpdU + (size_t)l * 16384, pUpdV + (size_t)l * 16384,
        pUpdW1 + (size_t)l * 32768, updb1 + (size_t)l * FDIM,
        pUpdW2 + (size_t)l * 49152, updb2 + (size_t)l * F3,
        mode,
        pMsgW1 + (size_t)lnext * 16384, msgb1 + (size_t)lnext * FDIM,
        pMsgW2 + (size_t)lnext * 49152, msgb2 + (size_t)lnext * F3,
        pRW1, rb1, rW2, rb2, atom_e);
  }
  mol_reduce_kernel<<<(NA + 255) / 256, 256, 0, stream>>>(atom_e, mol, (float*)d_out);
}

// Round 17
// 299.173 us; speedup vs baseline: 1.2318x; 1.0137x over previous
//
#include <hip/hip_runtime.h>
#include <hip/hip_bf16.h>
#include <math.h>

#define NA 10000
#define NE 256000
#define FDIM 128
#define F3 384
#define NRBF 20
#define NLAYERS 3
#define NMOLS 100
#define CAP 96
#define WROW 388  // padded w_lds row (bf16): conflict-free MFMA-C transpose (verified R6)
#define PACK_BLOCKS 2288  // 585728 / 256
#define CUTOFF_F 5.0f
#define EPS_F 1e-8f
#define PI_F 3.14159265358979323846f

typedef __attribute__((ext_vector_type(8))) short bf16x8;
typedef __attribute__((ext_vector_type(4))) float f32x4;

// 12-byte fused record: {phi0, phi1, phi2, v0, v1, v2} bf16
struct pv6 { unsigned int u0, u1, u2; };

__device__ __forceinline__ float silu_f(float x) { return x / (1.0f + __expf(-x)); }

__device__ __forceinline__ unsigned short f2bf(float x) {
  unsigned u = __float_as_uint(x);
  return (unsigned short)((u + 0x7FFFu + ((u >> 16) & 1u)) >> 16);
}
__device__ __forceinline__ float bf2f(unsigned short u) {
  return __uint_as_float(((unsigned)u) << 16);
}
__device__ __forceinline__ float lo_f(unsigned int u) { return bf2f((unsigned short)(u & 0xFFFFu)); }
__device__ __forceinline__ float hi_f(unsigned int u) { return bf2f((unsigned short)(u >> 16)); }

// ---------------- weight pack helpers -> B-fragment bf16 layout ----------------
__device__ __forceinline__ void pack_one(const float* __restrict__ src,
                                         unsigned short* __restrict__ dst,
                                         int loc, int per, int N) {
  int lay = loc / per;
  int kn = loc - lay * per;
  int k = kn / N, n = kn - k * N;
  int kb = k >> 5, q = (k >> 3) & 3, j = k & 7, nt = n >> 4, c = n & 15;
  int NT = N >> 4;
  dst[(size_t)lay * per + (((kb * NT + nt) * 64 + (q * 16 + c)) * 8 + j)] = f2bf(src[loc]);
}

// dist_W padded pack: K=32 (rows 0..19 = dW, row 20 = db, rest 0), N=384
__device__ __forceinline__ void pack_dw(const float* __restrict__ dW,
                                        const float* __restrict__ db,
                                        unsigned short* __restrict__ dst, int loc) {
  int lay = loc / 12288;
  int kn = loc - lay * 12288;
  int k = kn / 384, n = kn - k * 384;
  float val = 0.0f;
  if (k < NRBF) val = dW[lay * NRBF * 384 + k * 384 + n];
  else if (k == NRBF) val = db[lay * 384 + n];
  int q = (k >> 3) & 3, j = k & 7, nt = n >> 4, c = n & 15;
  dst[(size_t)lay * 12288 + ((nt * 64 + (q * 16 + c)) * 8 + j)] = f2bf(val);
}

// ---------------- merged prep: blocks [0,PACK_BLOCKS) = weight pack; rest = geometry ----------------
__global__ __launch_bounds__(256) void prep_kernel(
    const float* __restrict__ msgW1, const float* __restrict__ msgW2,
    const float* __restrict__ updU, const float* __restrict__ updV,
    const float* __restrict__ updW1, const float* __restrict__ updW2,
    const float* __restrict__ rW1, const float* __restrict__ distW,
    const float* __restrict__ distb, unsigned short* __restrict__ dst,
    const float* __restrict__ xyz, const int* __restrict__ nbrs,
    float* __restrict__ unitv, unsigned short* __restrict__ rbf_bf,
    float* __restrict__ fcut,
    int* __restrict__ deg, int* __restrict__ slot_e, int* __restrict__ slot_j) {
  int b = blockIdx.x;
  if (b < PACK_BLOCKS) {
    int t = b * 256 + threadIdx.x;
    if (t < 49152) pack_one(msgW1, dst, t, 16384, 128);
    else if (t < 196608) pack_one(msgW2, dst + 49152, t - 49152, 49152, 384);
    else if (t < 245760) pack_one(updU, dst + 196608, t - 196608, 16384, 128);
    else if (t < 294912) pack_one(updV, dst + 245760, t - 245760, 16384, 128);
    else if (t < 393216) pack_one(updW1, dst + 294912, t - 294912, 32768, 128);
    else if (t < 540672) pack_one(updW2, dst + 393216, t - 393216, 49152, 384);
    else if (t < 548864) pack_one(rW1, dst + 540672, t - 540672, 8192, 64);
    else if (t < 585728) pack_dw(distW, distb, dst + 548864, t - 548864);
    return;
  }
  int e = (b - PACK_BLOCKS) * 256 + threadIdx.x;
  if (e >= NE) return;
  int i = nbrs[2 * e + 0], j = nbrs[2 * e + 1];
  float rx = xyz[3 * j + 0] - xyz[3 * i + 0];
  float ry = xyz[3 * j + 1] - xyz[3 * i + 1];
  float rz = xyz[3 * j + 2] - xyz[3 * i + 2];
  float d = sqrtf(rx * rx + ry * ry + rz * rz + EPS_F);
  if (d >= CUTOFF_F) return;
  float invd = 1.0f / d;
  float fc = 0.5f * (__cosf(PI_F * d / CUTOFF_F) + 1.0f);
  unitv[3 * e + 0] = rx * invd;
  unitv[3 * e + 1] = ry * invd;
  unitv[3 * e + 2] = rz * invd;
  fcut[e] = fc;
  float base = PI_F * d / CUTOFF_F;
  float sc = invd * fc;
#pragma unroll
  for (int k = 0; k < NRBF; k++)
    rbf_bf[(size_t)e * NRBF + k] = f2bf(__sinf((float)(k + 1) * base) * sc);
  int pos = atomicAdd(&deg[i], 1);
  if (pos < CAP) {
    slot_e[i * CAP + pos] = e;
    slot_j[i * CAP + pos] = j;
  }
}

// ---------------- layer-0 message MLP (fused s = emb[z] init); writes pv6 {phi, v=0} ----------------
__global__ __launch_bounds__(256) void msg0_mfma_kernel(
    const float* __restrict__ emb, const int* __restrict__ z, float* __restrict__ s_out,
    const unsigned short* __restrict__ pW1, const float* __restrict__ b1,
    const unsigned short* __restrict__ pW2, const float* __restrict__ b2,
    pv6* __restrict__ cmb) {
  __shared__ bf16x8 sA[4 * 64];
  __shared__ bf16x8 hA[4 * 64];
  int a0 = blockIdx.x * 16;
  int t = threadIdx.x;
  int lane = t & 63, w = t >> 6;
  {
    int kb = t >> 6, l = t & 63;
    int m = l & 15, q = l >> 4;
    int zi = z[a0 + m];
    const float* sp = emb + (size_t)zi * FDIM + kb * 32 + q * 8;
    float* so = s_out + (size_t)(a0 + m) * FDIM + kb * 32 + q * 8;
    bf16x8 c;
#pragma unroll
    for (int j = 0; j < 8; j++) {
      float v = sp[j];
      so[j] = v;
      c[j] = (short)f2bf(v);
    }
    sA[kb * 64 + l] = c;
  }
  __syncthreads();
  f32x4 accH[2];
#pragma unroll
  for (int t2 = 0; t2 < 2; t2++)
#pragma unroll
    for (int r = 0; r < 4; r++) accH[t2][r] = 0.0f;
  const bf16x8* W1f = (const bf16x8*)pW1;
#pragma unroll
  for (int kb = 0; kb < 4; kb++) {
    bf16x8 a = sA[kb * 64 + lane];
#pragma unroll
    for (int t2 = 0; t2 < 2; t2++) {
      bf16x8 b = W1f[(kb * 8 + 2 * w + t2) * 64 + lane];
      accH[t2] = __builtin_amdgcn_mfma_f32_16x16x32_bf16(a, b, accH[t2], 0, 0, 0);
    }
  }
  short* hs = (short*)hA;
#pragma unroll
  for (int t2 = 0; t2 < 2; t2++) {
    int n = w * 32 + t2 * 16 + (lane & 15);
    int kb = n >> 5, q = (n >> 3) & 3, j = n & 7;
    float bias = b1[n];
#pragma unroll
    for (int r = 0; r < 4; r++) {
      int m = (lane >> 4) * 4 + r;
      hs[(kb * 64 + q * 16 + m) * 8 + j] = (short)f2bf(silu_f(accH[t2][r] + bias));
    }
  }
  __syncthreads();
  f32x4 accP[3][2];
#pragma unroll
  for (int c3 = 0; c3 < 3; c3++)
#pragma unroll
    for (int t2 = 0; t2 < 2; t2++)
#pragma unroll
      for (int r = 0; r < 4; r++) accP[c3][t2][r] = 0.0f;
  const bf16x8* W2f = (const bf16x8*)pW2;
#pragma unroll
  for (int kb = 0; kb < 4; kb++) {
    bf16x8 a = hA[kb * 64 + lane];
#pragma unroll
    for (int c3 = 0; c3 < 3; c3++)
#pragma unroll
      for (int t2 = 0; t2 < 2; t2++) {
        bf16x8 b = W2f[(kb * 24 + c3 * 8 + 2 * w + t2) * 64 + lane];
        accP[c3][t2] = __builtin_amdgcn_mfma_f32_16x16x32_bf16(a, b, accP[c3][t2], 0, 0, 0);
      }
  }
#pragma unroll
  for (int t2 = 0; t2 < 2; t2++) {
    int g = (2 * w + t2) * 16 + (lane & 15);
    float bb0 = b2[g], bb1 = b2[FDIM + g], bb2 = b2[2 * FDIM + g];
#pragma unroll
    for (int r = 0; r < 4; r++) {
      int m = (lane >> 4) * 4 + r;
      unsigned p0 = f2bf(accP[0][t2][r] + bb0);
      unsigned p1 = f2bf(accP[1][t2][r] + bb1);
      unsigned p2 = f2bf(accP[2][t2][r] + bb2);
      pv6 rec;
      rec.u0 = p0 | (p1 << 16);
      rec.u1 = p2;
      rec.u2 = 0;
      cmb[(size_t)(a0 + m) * FDIM + g] = rec;
    }
  }
}

// ---------------- edge aggregation: 128 thr, 12B pv6 gather, 4-edge unrolled MLP ----------------
__global__ __launch_bounds__(128) void edge_kernel(
    const pv6* __restrict__ cmb, unsigned short* __restrict__ v_lin,
    float* __restrict__ s, const unsigned short* __restrict__ pDW,
    const int* __restrict__ deg, const int* __restrict__ slot_e,
    const int* __restrict__ slot_j, const unsigned short* __restrict__ rbf_bf,
    const float* __restrict__ fcut, const float* __restrict__ unitv) {
  __shared__ bf16x8 aLDS[64];
  __shared__ unsigned short w_lds[16][WROW];
  __shared__ float l_u[16][3];
  __shared__ int l_j[16];
  int i = blockIdx.x;
  int t = threadIdx.x;
  int f = t;
  int lane = t & 63, w = t >> 6;
  int cnt = deg[i];
  if (cnt > CAP) cnt = CAP;
  int base = i * CAP;
  float acc_s = 0.f, av0 = 0.f, av1 = 0.f, av2 = 0.f;
  const bf16x8* Bf = (const bf16x8*)pDW;
  for (int c0 = 0; c0 < cnt; c0 += 16) {
    int ccnt = cnt - c0;
    if (ccnt > 16) ccnt = 16;
    __syncthreads();  // prev chunk's LDS reads done before overwrite
    if (t < 64) {
      int m = t & 15, q = t >> 4;
      bf16x8 a;
#pragma unroll
      for (int j = 0; j < 8; j++) a[j] = 0;
      int p = c0 + m;
      if (p < cnt) {
        int e = slot_e[base + p];
        const unsigned short* rb = rbf_bf + (size_t)e * NRBF;
#pragma unroll
        for (int j = 0; j < 8; j++) {
          int k = q * 8 + j;
          if (k < NRBF) a[j] = (short)rb[k];
          else if (k == NRBF) a[j] = (short)f2bf(fcut[e]);
        }
      }
      aLDS[t] = a;
    } else if (t < 80) {
      int idx = t - 64;
      int p = c0 + idx;
      if (p < cnt) {
        int e = slot_e[base + p];
        l_j[idx] = slot_j[base + p];
        l_u[idx][0] = unitv[3 * e + 0];
        l_u[idx][1] = unitv[3 * e + 1];
        l_u[idx][2] = unitv[3 * e + 2];
      }
    }
    __syncthreads();
    {
      bf16x8 a = aLDS[lane];
      int n0 = lane & 15, m0 = (lane >> 4) * 4;
#pragma unroll
      for (int tt = 0; tt < 12; tt++) {
        int nt = 12 * w + tt;
        f32x4 acc;
#pragma unroll
        for (int r = 0; r < 4; r++) acc[r] = 0.0f;
        acc = __builtin_amdgcn_mfma_f32_16x16x32_bf16(a, Bf[nt * 64 + lane], acc, 0, 0, 0);
        int n = nt * 16 + n0;
#pragma unroll
        for (int r = 0; r < 4; r++) w_lds[m0 + r][n] = f2bf(acc[r]);
      }
    }
    __syncthreads();
    int pp = 0;
    for (; pp + 4 <= ccnt; pp += 4) {
      // batch all 4 gathers first -> 4x12B in flight per lane
      pv6 R[4];
#pragma unroll
      for (int u = 0; u < 4; u++) R[u] = cmb[(size_t)l_j[pp + u] * FDIM + f];
#pragma unroll
      for (int u = 0; u < 4; u++) {
        float p0 = lo_f(R[u].u0), p1 = hi_f(R[u].u0), p2 = lo_f(R[u].u1);
        float v0 = hi_f(R[u].u1), v1 = lo_f(R[u].u2), v2 = hi_f(R[u].u2);
        float w0 = bf2f(w_lds[pp + u][f]), w1 = bf2f(w_lds[pp + u][FDIM + f]),
              w2 = bf2f(w_lds[pp + u][2 * FDIM + f]);
        acc_s += p0 * w0;
        float i1 = p1 * w1, i2 = p2 * w2;
        av0 += i1 * v0 + i2 * l_u[pp + u][0];
        av1 += i1 * v1 + i2 * l_u[pp + u][1];
        av2 += i1 * v2 + i2 * l_u[pp + u][2];
      }
    }
    for (; pp < ccnt; pp++) {
      pv6 R0 = cmb[(size_t)l_j[pp] * FDIM + f];
      float p0 = lo_f(R0.u0), p1 = hi_f(R0.u0), p2 = lo_f(R0.u1);
      float v0 = hi_f(R0.u1), v1 = lo_f(R0.u2), v2 = hi_f(R0.u2);
      float w0 = bf2f(w_lds[pp][f]), w1 = bf2f(w_lds[pp][FDIM + f]),
            w2 = bf2f(w_lds[pp][2 * FDIM + f]);
      acc_s += p0 * w0;
      float i1 = p1 * w1, i2 = p2 * w2;
      av0 += i1 * v0 + i2 * l_u[pp][0];
      av1 += i1 * v1 + i2 * l_u[pp][1];
      av2 += i1 * v2 + i2 * l_u[pp][2];
    }
  }
  // own-atom v add: cmb v-halves are 0 for layer 0, so unconditional is correct
  {
    pv6 RI = cmb[(size_t)i * FDIM + f];
    av0 += hi_f(RI.u1);
    av1 += lo_f(RI.u2);
    av2 += hi_f(RI.u2);
  }
  unsigned short* vlo = v_lin + (size_t)i * F3;
  vlo[f] = f2bf(av0);
  vlo[FDIM + f] = f2bf(av1);
  vlo[2 * FDIM + f] = f2bf(av2);
  s[(size_t)i * FDIM + f] += acc_s;
}

// ---------------- fused update (+ next-layer msg, or atom-energy readout) ----------------
// v_old re-read from vAf LDS (still live); u2 stored in s-epilogue; v0 kept in regs for msg epilogue.
__global__ __launch_bounds__(256) void upd_fused_kernel(
    float* __restrict__ s, const unsigned short* __restrict__ v_lin,
    pv6* __restrict__ cmb,
    const unsigned short* __restrict__ pU, const unsigned short* __restrict__ pV,
    const unsigned short* __restrict__ pW1, const float* __restrict__ b1,
    const unsigned short* __restrict__ pW2, const float* __restrict__ b2,
    int mode,
    const unsigned short* __restrict__ pMW1, const float* __restrict__ mb1,
    const unsigned short* __restrict__ pMW2, const float* __restrict__ mb2,
    const unsigned short* __restrict__ pRW1, const float* __restrict__ rb1,
    const float* __restrict__ rW2, const float* __restrict__ rb2,
    float* __restrict__ atom_e) {
  __shared__ bf16x8 vAf[3 * 4 * 64];
  __shared__ bf16x8 catA[8 * 64];
  __shared__ bf16x8 hA[4 * 64];
  __shared__ float red[4][16];
  int a0 = blockIdx.x * 16;
  int t = threadIdx.x;
  int lane = t & 63, w = t >> 6;
  {
    int l = t & 63, kb = (t >> 6) & 3;
    int m = l & 15, q = l >> 4;
#pragma unroll
    for (int rt = 0; rt < 3; rt++) {
      vAf[(rt * 4 + kb) * 64 + l] =
          *(const bf16x8*)(v_lin + (size_t)(a0 + m) * F3 + rt * FDIM + kb * 32 + q * 8);
    }
    const float* sp = s + (size_t)(a0 + m) * FDIM + kb * 32 + q * 8;
    bf16x8 c;
#pragma unroll
    for (int j = 0; j < 8; j++) c[j] = (short)f2bf(sp[j]);
    catA[kb * 64 + l] = c;
  }
  __syncthreads();
  f32x4 accU[3][2], accV[3][2];
#pragma unroll
  for (int rt = 0; rt < 3; rt++)
#pragma unroll
    for (int t2 = 0; t2 < 2; t2++)
#pragma unroll
      for (int r = 0; r < 4; r++) { accU[rt][t2][r] = 0.0f; accV[rt][t2][r] = 0.0f; }
  const bf16x8* Uf = (const bf16x8*)pU;
  const bf16x8* Vf = (const bf16x8*)pV;
#pragma unroll
  for (int kb = 0; kb < 4; kb++) {
    bf16x8 bu[2], bv[2];
#pragma unroll
    for (int t2 = 0; t2 < 2; t2++) {
      bu[t2] = Uf[(kb * 8 + 2 * w + t2) * 64 + lane];
      bv[t2] = Vf[(kb * 8 + 2 * w + t2) * 64 + lane];
    }
#pragma unroll
    for (int rt = 0; rt < 3; rt++) {
      bf16x8 a = vAf[(rt * 4 + kb) * 64 + lane];
#pragma unroll
      for (int t2 = 0; t2 < 2; t2++) {
        accU[rt][t2] = __builtin_amdgcn_mfma_f32_16x16x32_bf16(a, bu[t2], accU[rt][t2], 0, 0, 0);
        accV[rt][t2] = __builtin_amdgcn_mfma_f32_16x16x32_bf16(a, bv[t2], accV[rt][t2], 0, 0, 0);
      }
    }
  }
  short* cs = (short*)catA;
#pragma unroll
  for (int t2 = 0; t2 < 2; t2++) {
    int g = w * 32 + t2 * 16 + (lane & 15);
    int k = 128 + g;
    int kb = k >> 5, q = (k >> 3) & 3, j = k & 7;
#pragma unroll
    for (int r = 0; r < 4; r++) {
      int m = (lane >> 4) * 4 + r;
      float x0 = accV[0][t2][r], x1 = accV[1][t2][r], x2 = accV[2][t2][r];
      cs[(kb * 64 + q * 16 + m) * 8 + j] = (short)f2bf(sqrtf(x0 * x0 + x1 * x1 + x2 * x2 + EPS_F));
    }
  }
  __syncthreads();
  f32x4 accH[2];
#pragma unroll
  for (int t2 = 0; t2 < 2; t2++)
#pragma unroll
    for (int r = 0; r < 4; r++) accH[t2][r] = 0.0f;
  const bf16x8* W1f = (const bf16x8*)pW1;
#pragma unroll
  for (int kb = 0; kb < 8; kb++) {
    bf16x8 a = catA[kb * 64 + lane];
#pragma unroll
    for (int t2 = 0; t2 < 2; t2++) {
      bf16x8 b = W1f[(kb * 8 + 2 * w + t2) * 64 + lane];
      accH[t2] = __builtin_amdgcn_mfma_f32_16x16x32_bf16(a, b, accH[t2], 0, 0, 0);
    }
  }
  short* hs = (short*)hA;
#pragma unroll
  for (int t2 = 0; t2 < 2; t2++) {
    int n = w * 32 + t2 * 16 + (lane & 15);
    int kb = n >> 5, q = (n >> 3) & 3, j = n & 7;
    float bias = b1[n];
#pragma unroll
    for (int r = 0; r < 4; r++) {
      int m = (lane >> 4) * 4 + r;
      hs[(kb * 64 + q * 16 + m) * 8 + j] = (short)f2bf(silu_f(accH[t2][r] + bias));
    }
  }
  __syncthreads();
  f32x4 accA[3][2];
#pragma unroll
  for (int c3 = 0; c3 < 3; c3++)
#pragma unroll
    for (int t2 = 0; t2 < 2; t2++)
#pragma unroll
      for (int r = 0; r < 4; r++) accA[c3][t2][r] = 0.0f;
  const bf16x8* W2f = (const bf16x8*)pW2;
#pragma unroll
  for (int kb = 0; kb < 4; kb++) {
    bf16x8 a = hA[kb * 64 + lane];
#pragma unroll
    for (int c3 = 0; c3 < 3; c3++)
#pragma unroll
      for (int t2 = 0; t2 < 2; t2++) {
        bf16x8 b = W2f[(kb * 24 + c3 * 8 + 2 * w + t2) * 64 + lane];
        accA[c3][t2] = __builtin_amdgcn_mfma_f32_16x16x32_bf16(a, b, accA[c3][t2], 0, 0, 0);
      }
  }
  const short* vls = (const short*)vAf;  // v_old still live in LDS A-frag layout
  unsigned short v0keep[2][4];
#pragma unroll
  for (int t2 = 0; t2 < 2; t2++) {
    int g = w * 32 + t2 * 16 + (lane & 15);
    float bb0 = b2[g], bb1 = b2[FDIM + g], bb2 = b2[2 * FDIM + g];
    int kb = g >> 5, q = (g >> 3) & 3, j = g & 7;
#pragma unroll
    for (int r = 0; r < 4; r++) {
      int m = (lane >> 4) * 4 + r;
      int n = a0 + m;
      float a0v = accA[0][t2][r] + bb0;
      float a1v = accA[1][t2][r] + bb1;
      float a2v = accA[2][t2][r] + bb2;
      float dot = accU[0][t2][r] * accV[0][t2][r] + accU[1][t2][r] * accV[1][t2][r] +
                  accU[2][t2][r] * accV[2][t2][r];
      float s_new = s[(size_t)n * FDIM + g] + a1v * dot + a2v;
      if (mode == 0) {
        s[(size_t)n * FDIM + g] = s_new;
        float nv[3];
#pragma unroll
        for (int c = 0; c < 3; c++) {
          float vold = bf2f((unsigned short)vls[(((c * 4 + kb) * 64) + (q * 16 + m)) * 8 + j]);
          nv[c] = vold + a0v * accU[c][t2][r];
        }
        v0keep[t2][r] = f2bf(nv[0]);
        cmb[(size_t)n * FDIM + g].u2 = (unsigned)f2bf(nv[1]) | ((unsigned)f2bf(nv[2]) << 16);
      }
      cs[(kb * 64 + q * 16 + m) * 8 + j] = (short)f2bf(s_new);
    }
  }
  __syncthreads();
  if (mode == 0) {
    f32x4 accH2[2];
#pragma unroll
    for (int t2 = 0; t2 < 2; t2++)
#pragma unroll
      for (int r = 0; r < 4; r++) accH2[t2][r] = 0.0f;
    const bf16x8* MW1f = (const bf16x8*)pMW1;
#pragma unroll
    for (int kb = 0; kb < 4; kb++) {
      bf16x8 a = catA[kb * 64 + lane];
#pragma unroll
      for (int t2 = 0; t2 < 2; t2++) {
        bf16x8 b = MW1f[(kb * 8 + 2 * w + t2) * 64 + lane];
        accH2[t2] = __builtin_amdgcn_mfma_f32_16x16x32_bf16(a, b, accH2[t2], 0, 0, 0);
      }
    }
#pragma unroll
    for (int t2 = 0; t2 < 2; t2++) {
      int n = w * 32 + t2 * 16 + (lane & 15);
      int kb = n >> 5, q = (n >> 3) & 3, j = n & 7;
      float bias = mb1[n];
#pragma unroll
      for (int r = 0; r < 4; r++) {
        int m = (lane >> 4) * 4 + r;
        hs[(kb * 64 + q * 16 + m) * 8 + j] = (short)f2bf(silu_f(accH2[t2][r] + bias));
      }
    }
    __syncthreads();
    f32x4 accP[3][2];
#pragma unroll
    for (int c3 = 0; c3 < 3; c3++)
#pragma unroll
      for (int t2 = 0; t2 < 2; t2++)
#pragma unroll
        for (int r = 0; r < 4; r++) accP[c3][t2][r] = 0.0f;
    const bf16x8* MW2f = (const bf16x8*)pMW2;
#pragma unroll
    for (int kb = 0; kb < 4; kb++) {
      bf16x8 a = hA[kb * 64 + lane];
#pragma unroll
      for (int c3 = 0; c3 < 3; c3++)
#pragma unroll
        for (int t2 = 0; t2 < 2; t2++) {
          bf16x8 b = MW2f[(kb * 24 + c3 * 8 + 2 * w + t2) * 64 + lane];
          accP[c3][t2] = __builtin_amdgcn_mfma_f32_16x16x32_bf16(a, b, accP[c3][t2], 0, 0, 0);
        }
    }
#pragma unroll
    for (int t2 = 0; t2 < 2; t2++) {
      int g = (2 * w + t2) * 16 + (lane & 15);
      float bb0 = mb2[g], bb1 = mb2[FDIM + g], bb2v = mb2[2 * FDIM + g];
#pragma unroll
      for (int r = 0; r < 4; r++) {
        int m = (lane >> 4) * 4 + r;
        unsigned p0 = f2bf(accP[0][t2][r] + bb0);
        unsigned p1 = f2bf(accP[1][t2][r] + bb1);
        unsigned p2 = f2bf(accP[2][t2][r] + bb2v);
        pv6* rec = &cmb[(size_t)(a0 + m) * FDIM + g];
        rec->u0 = p0 | (p1 << 16);
        rec->u1 = p2 | ((unsigned)v0keep[t2][r] << 16);
      }
    }
  } else {
    f32x4 acc;
#pragma unroll
    for (int r = 0; r < 4; r++) acc[r] = 0.0f;
    const bf16x8* RW1f = (const bf16x8*)pRW1;
#pragma unroll
    for (int kb = 0; kb < 4; kb++) {
      bf16x8 a = catA[kb * 64 + lane];
      bf16x8 b = RW1f[(kb * 4 + w) * 64 + lane];
      acc = __builtin_amdgcn_mfma_f32_16x16x32_bf16(a, b, acc, 0, 0, 0);
    }
    int col = w * 16 + (lane & 15);
    float bias = rb1[col], w2v = rW2[col];
    float val[4];
#pragma unroll
    for (int r = 0; r < 4; r++) val[r] = silu_f(acc[r] + bias) * w2v;
#pragma unroll
    for (int off = 1; off < 16; off <<= 1)
#pragma unroll
      for (int r = 0; r < 4; r++) val[r] += __shfl_xor(val[r], off, 64);
    if ((lane & 15) == 0) {
#pragma unroll
      for (int r = 0; r < 4; r++) red[w][(lane >> 4) * 4 + r] = val[r];
    }
    __syncthreads();
    if (t < 16) {
      atom_e[a0 + t] = red[0][t] + red[1][t] + red[2][t] + red[3][t] + rb2[0];
    }
  }
}

// ---------------- molecule segment-sum: LDS partials, ~3 global atomics per block ----------------
__global__ __launch_bounds__(256) void mol_reduce_kernel(
    const float* __restrict__ atom_e, const int* __restrict__ mol_idx,
    float* __restrict__ out) {
  __shared__ float molsum[NMOLS];
  int t = threadIdx.x;
  if (t < NMOLS) molsum[t] = 0.0f;
  __syncthreads();
  int n = blockIdx.x * 256 + t;
  if (n < NA) atomicAdd(&molsum[mol_idx[n]], atom_e[n]);
  __syncthreads();
  if (t < NMOLS && molsum[t] != 0.0f) atomicAdd(&out[t], molsum[t]);
}

extern "C" void kernel_launch(void* const* d_in, const int* in_sizes, int n_in,
                              void* d_out, int out_size, void* d_ws, size_t ws_size,
                              hipStream_t stream) {
  const float* xyz = (const float*)d_in[0];
  const int* z = (const int*)d_in[1];
  const int* nbrs = (const int*)d_in[2];
  const int* mol = (const int*)d_in[3];
  const float* emb = (const float*)d_in[4];
  const float* msgW1 = (const float*)d_in[5];
  const float* msgb1 = (const float*)d_in[6];
  const float* msgW2 = (const float*)d_in[7];
  const float* msgb2 = (const float*)d_in[8];
  const float* distW = (const float*)d_in[9];
  const float* distb = (const float*)d_in[10];
  const float* updU = (const float*)d_in[11];
  const float* updV = (const float*)d_in[12];
  const float* updW1 = (const float*)d_in[13];
  const float* updb1 = (const float*)d_in[14];
  const float* updW2 = (const float*)d_in[15];
  const float* updb2 = (const float*)d_in[16];
  const float* rW1 = (const float*)d_in[17];
  const float* rb1 = (const float*)d_in[18];
  const float* rW2 = (const float*)d_in[19];
  const float* rb2 = (const float*)d_in[20];

  float* ws = (float*)d_ws;
  float* s = ws;      ws += (size_t)NA * FDIM;
  float* fcut = ws;   ws += (size_t)NE;
  float* unitv = ws;  ws += (size_t)NE * 3;
  float* atom_e = ws; ws += (size_t)NA;
  int* deg = (int*)ws;
  int* slot_e = deg + NA;
  int* slot_j = slot_e + NA * CAP;
  unsigned short* pk = (unsigned short*)(((uintptr_t)(slot_j + NA * CAP) + 15) & ~(uintptr_t)15);
  unsigned short* pMsgW1 = pk;                       // 49152
  unsigned short* pMsgW2 = pMsgW1 + 49152;           // 147456
  unsigned short* pUpdU  = pMsgW2 + 147456;          // 49152
  unsigned short* pUpdV  = pUpdU + 49152;            // 49152
  unsigned short* pUpdW1 = pUpdV + 49152;            // 98304
  unsigned short* pUpdW2 = pUpdW1 + 98304;           // 147456
  unsigned short* pRW1   = pUpdW2 + 147456;          // 8192
  unsigned short* pDW    = pRW1 + 8192;              // 3*12288
  unsigned short* rbf_bf = (unsigned short*)(((uintptr_t)(pDW + 36864) + 15) & ~(uintptr_t)15);
  unsigned short* after_rbf = rbf_bf + (size_t)NE * NRBF + 8;
  pv6* cmb = (pv6*)(((uintptr_t)after_rbf + 15) & ~(uintptr_t)15);           // NA*128 x 12B
  unsigned short* v_lin = (unsigned short*)(cmb + (size_t)NA * FDIM);        // NA*384

  hipMemsetAsync(deg, 0, NA * sizeof(int), stream);
  hipMemsetAsync(d_out, 0, NMOLS * sizeof(float), stream);

  prep_kernel<<<PACK_BLOCKS + NE / 256, 256, 0, stream>>>(
      msgW1, msgW2, updU, updV, updW1, updW2, rW1, distW, distb, pMsgW1,
      xyz, nbrs, unitv, rbf_bf, fcut, deg, slot_e, slot_j);
  msg0_mfma_kernel<<<NA / 16, 256, 0, stream>>>(emb, z, s, pMsgW1, msgb1, pMsgW2, msgb2, cmb);

  for (int l = 0; l < NLAYERS; l++) {
    edge_kernel<<<NA, 128, 0, stream>>>(cmb, v_lin, s,
                                        pDW + (size_t)l * 12288,
                                        deg, slot_e, slot_j, rbf_bf, fcut, unitv);
    int mode = (l == NLAYERS - 1) ? 1 : 0;
    int lnext = (l + 1 < NLAYERS) ? l + 1 : 0;
    upd_fused_kernel<<<NA / 16, 256, 0, stream>>>(
        s, v_lin, cmb, pUpdU + (size_t)l * 16384, pUpdV + (size_t)l * 16384,
        pUpdW1 + (size_t)l * 32768, updb1 + (size_t)l * FDIM,
        pUpdW2 + (size_t)l * 49152, updb2 + (size_t)l * F3,
        mode,
        pMsgW1 + (size_t)lnext * 16384, msgb1 + (size_t)lnext * FDIM,
        pMsgW2 + (size_t)lnext * 49152, msgb2 + (size_t)lnext * F3,
        pRW1, rb1, rW2, rb2, atom_e);
  }
  mol_reduce_kernel<<<(NA + 255) / 256, 256, 0, stream>>>(atom_e, mol, (float*)d_out);
}